// Round 7
// baseline (1966.121 us; speedup 1.0000x reference)
//
#include <hip/hip_runtime.h>
#include <hip/hip_fp16.h>

typedef _Float16 f16;
typedef _Float16 f16x8 __attribute__((ext_vector_type(8)));
typedef float    f32x4 __attribute__((ext_vector_type(4)));
typedef unsigned short ushort;
typedef unsigned int uint;
typedef unsigned long long u64;

__device__ __forceinline__ float sigm(float x) { return 1.f / (1.f + __expf(-x)); }
__device__ __forceinline__ float reluf(float x) { return x > 0.f ? x : 0.f; }
__device__ __forceinline__ float h2f(ushort u) { return (float)__builtin_bit_cast(f16, u); }
__device__ __forceinline__ ushort f2h(float v) { return __builtin_bit_cast(ushort, (f16)v); }

#define LDRLX(p)    __hip_atomic_load((p), __ATOMIC_RELAXED, __HIP_MEMORY_SCOPE_AGENT)
#define STRLX(p, v) __hip_atomic_store((p), (v), __ATOMIC_RELAXED, __HIP_MEMORY_SCOPE_AGENT)
#define MFMA16(a, b, c) __builtin_amdgcn_mfma_f32_16x16x32_f16((a), (b), (c), 0, 0, 0)
// lgkm-only barrier: orders LDS without draining vmcnt (ring publishes stay in
// flight across step barriers; correctness = tag-in-data + backpressure).
#define LBAR() do { asm volatile("s_waitcnt lgkmcnt(0)" ::: "memory"); \
                    __builtin_amdgcn_s_barrier(); } while (0)

// Backpressure poll (agent scope; amortized off critical path).
__device__ __forceinline__ void poll_all(uint* p, uint need, bool act) {
  bool done = !act;
  while (true) {
    if (!done) done = (LDRLX(p) >= need);
    if (__all((int)done)) break;
    __builtin_amdgcn_s_sleep(1);
  }
}

__device__ __forceinline__ u64 ldr64(const u64* p) {
  return __hip_atomic_load(p, __ATOMIC_RELAXED, __HIP_MEMORY_SCOPE_AGENT);
}
__device__ __forceinline__ void str64(u64* p, u64 v) {
  __hip_atomic_store(p, v, __ATOMIC_RELAXED, __HIP_MEMORY_SCOPE_AGENT);
}

// Tag-in-data record poll: each u64 record = {tag:32 | payload(2xf16):32}.
template <int NR>
__device__ __forceinline__ void poll_recs(const u64* const (&ra)[NR],
                                          const uint (&nd)[NR], u64 (&rv)[NR]) {
  bool ok[NR];
#pragma unroll
  for (int i = 0; i < NR; i++) ok[i] = (nd[i] == 0u);
  while (true) {
    bool all = true;
#pragma unroll
    for (int i = 0; i < NR; i++) if (!ok[i]) rv[i] = ldr64(ra[i]);
#pragma unroll
    for (int i = 0; i < NR; i++) if (!ok[i]) ok[i] = ((uint)(rv[i] >> 32) >= nd[i]);
#pragma unroll
    for (int i = 0; i < NR; i++) all &= ok[i];
    if (all) return;
    __builtin_amdgcn_s_sleep(1);
  }
}

// ---------------- pack B for MFMA b-frag layout (validated R1-R6)
template <int KF>
__global__ void pack_bsw(const float* __restrict__ B, f16* __restrict__ dst, int N) {
  int id = blockIdx.x * 256 + threadIdx.x;
  int total = KF * 32 * N;
  if (id >= total) return;
  int j  = id & 7;
  int L  = (id >> 3) & 63;
  int r  = id >> 9;
  int kf = r & (KF - 1);
  int c  = r / KF;
  int k  = kf * 32 + ((L >> 4) * 8) + j;
  int n  = c * 16 + (L & 15);
  dst[id] = (f16)B[k * N + n];
}

// ---------------- xW GEMM. MODE0 para: X[g][t][gate4][u256][s16]. MODE1 title:
// X[g][t][gate4][u128][s16].  (s = quad*4+r rows of the MFMA C tile = seq index)
template <int Sx, int K, int KF, int N, int NC, int MODE>
__global__ __launch_bounds__(256) void gemm_xw(const int* __restrict__ tok,
                                               const float* __restrict__ emb,
                                               const f16* __restrict__ Bsw,
                                               const float* __restrict__ bias,
                                               f16* __restrict__ X) {
  __shared__ int tokLds[64];
  __shared__ f16x8 bLds[8 * 64];
  const int tid = threadIdx.x;
  const int blk = blockIdx.x;
  const int g  = (MODE == 0) ? (blk >> 7) : (blk >> 4);
  const int t0 = (MODE == 0) ? ((blk & 127) * 4) : ((blk & 15) * 4);
  if (tid < 64) {
    int wv = tid >> 4, rho = tid & 15;
    tokLds[tid] = tok[(g * 16 + rho) * Sx + t0 + wv];
  }
  __syncthreads();
  const int wave = tid >> 6, lane = tid & 63;
  const int quad = lane >> 4, l16 = lane & 15;

  f16x8 a[KF];
  {
    const float* arow = emb + (long)tokLds[wave * 16 + l16] * K + quad * 8;
#pragma unroll
    for (int kf = 0; kf < KF; kf++) {
      float4 v0 = *(const float4*)(arow + kf * 32);
      float4 v1 = *(const float4*)(arow + kf * 32 + 4);
      f16x8 tv;
      tv[0] = (f16)v0.x; tv[1] = (f16)v0.y; tv[2] = (f16)v0.z; tv[3] = (f16)v0.w;
      tv[4] = (f16)v1.x; tv[5] = (f16)v1.y; tv[6] = (f16)v1.z; tv[7] = (f16)v1.w;
      a[kf] = tv;
    }
  }
  const int t = t0 + wave;
  const f16x8* Bfrag = (const f16x8*)Bsw;
  for (int c = 0; c < NC; c++) {
    for (int i = tid; i < KF * 64; i += 256) bLds[i] = Bfrag[c * KF * 64 + i];
    __syncthreads();
    f32x4 acc = {0.f, 0.f, 0.f, 0.f};
#pragma unroll
    for (int kf = 0; kf < KF; kf++)
      acc = MFMA16(a[kf], bLds[kf * 64 + lane], acc);
    const int col = c * 16 + l16;
    const float bc = bias[col];
    uint2 pk;
    pk.x = (uint)f2h(acc[0] + bc) | ((uint)f2h(acc[1] + bc) << 16);
    pk.y = (uint)f2h(acc[2] + bc) | ((uint)f2h(acc[3] + bc) << 16);
    size_t base;
    if (MODE == 0) {
      int gm = col >> 8, u = col & 255;
      base = (((size_t)(g * 512 + t) * 4 + gm) * 4096) + u * 16 + quad * 4;
    } else {
      int gm = col >> 7, u = col & 127;
      base = (((size_t)(g * 64 + t) * 4 + gm) * 2048) + u * 16 + quad * 4;
    }
    *(uint2*)(X + base) = pk;
    __syncthreads();
  }
}

// ---------------- pipelined persistent recurrence: 56 blocks x 256 thr
// R13: 2-block wide stages with weights mostly in VGPRs (1 wave/SIMD ->
// 512-reg budget via __launch_bounds__(256,1); R4 lesson: per-SIMD unified
// pool is 512, so 2 waves/EU caps at 256 and spills).
// role = blk>>3, g = blk&7. roles: 0-1 paraL0(bb), 2-3 paraL1(bn),
// 4 paraL2+tail, 5 titleL0 (single block, intra-CU recurrence, no ring),
// 6 titleL1+tail.
// Protocol: tag-in-data rings (verified R8), coalesced thread-linear record
// maps, LBAR step barriers, cnt[] backpressure every 4 steps (depth 8 >
// window 4 + drift<=1). Rings+cnt zeroed every replay.
// Record maps (producer-linear, tid = w*64+lane in 256-thr blocks):
//   h0r:  slot*2048 + bb*1024 + tid*4 + ut*2 + j
//         = h rows (quad*4+2j, +1) of unit 128bb+32w+16ut+l16
//   h1r:  slot*1024 + bn*512 + tid*2 + j
//         = h rows (quad*4+2j, +1) of unit 64bn+16w+l16
//   h0tr: slot*1024 + tid*4 + ut*2 + j
//         = h rows (quad*4+2j, +1) of unit 32w+16ut+l16
struct RP {
  const f16 *xp2, *xt2;
  const f16 *U0f, *W1f, *U1f, *W2f, *U2f, *U0tf, *W1tf, *U1tf;
  const float *pl1_b, *pl2_b, *tl1_b;
  const float *pd0W, *pd0b, *pd1W, *pd1b, *pd2W, *pd2b;
  const float *td0W, *td0b, *td1W, *td1b, *td2W, *td2b;
  u64 *h0r, *h1r, *h0tr;
  uint *cnt;
  float* feat;
};

__global__ __launch_bounds__(256, 1) void recur_pipe(RP A) {
  __shared__ __align__(16) char smem[139776];
  const int tid = threadIdx.x;
  const int w = tid >> 6, lane = tid & 63;
  const int quad = lane >> 4, l16 = lane & 15;
  const int blk = blockIdx.x;
  const int role = blk >> 3, g = blk & 7;
  uint* mytag = A.cnt + (role * 8 + g) * 16;

  if (role < 2) {
    // ============ paragraph L0: 2 blocks, 128 units each ====================
    // wave w owns unit-tiles {2w, 2w+1} within its block (32 units), all 4
    // gates. Weights: kf 0-5 in VGPRs (48 frags), kf 6-7 in LDS (64 frags).
    const int bb = role, pbb = bb ^ 1;
    f16x8* wl8 = (f16x8*)smem;                  // 64KB: 64 frags x 64 lanes
    f16* hb = (f16*)(smem + 65536);             // [2][16*264]
    f16x8 wr[2][4][6];
    {
      const f16x8* U0f8 = (const f16x8*)A.U0f;
#pragma unroll
      for (int ut = 0; ut < 2; ut++)
#pragma unroll
        for (int gm = 0; gm < 4; gm++)
#pragma unroll
          for (int kf = 0; kf < 6; kf++)
            wr[ut][gm][kf] =
                U0f8[((gm * 16 + bb * 8 + w * 2 + ut) * 8 + kf) * 64 + lane];
      // LDS frags: fragid = w*16 + ut*8 + gm*2 + kfo   (kf = 6 + kfo)
      const uint4* U0q = (const uint4*)A.U0f;
      uint4* wq = (uint4*)wl8;
      for (int idx = tid; idx < 4096; idx += 256) {
        int fragid = idx >> 6, ln = idx & 63;
        int wf = fragid >> 4, ut = (fragid >> 3) & 1, gm = (fragid >> 1) & 3,
            kfo = fragid & 1;
        wq[idx] = U0q[((gm * 16 + bb * 8 + wf * 2 + ut) * 8 + 6 + kfo) * 64 + ln];
      }
    }
    for (int idx = tid; idx < 8448; idx += 256) hb[idx] = (f16)0.f;
    float c0[2][4] = {};
    u64* ringg = A.h0r + (size_t)g * 16384;
    const uint2* xq2 = (const uint2*)A.xp2;
    uint* bpp = A.cnt;
    if (lane < 2) bpp = A.cnt + ((2 + lane) * 8 + g) * 16;   // L1 consumption
    __syncthreads();

    for (int t = 0; t < 512; t++) {
      uint2 xv[2][4];
#pragma unroll
      for (int ut = 0; ut < 2; ut++) {
        const int myu = 128 * bb + 32 * w + 16 * ut + l16;
        size_t xb = ((size_t)(g * 512 + t) * 4) * 1024 + (size_t)myu * 4 + quad;
#pragma unroll
        for (int gm = 0; gm < 4; gm++) xv[ut][gm] = xq2[xb + (size_t)gm * 1024];
      }
      poll_all(bpp, t > 4 ? (uint)(t - 4) : 0u,
               (lane < 2) && (t > 0) && ((t & 3) == 0));
      {
        const u64* slotb = ringg + (size_t)((t + 7) & 7) * 2048 + pbb * 1024;
        const u64* ra[4]; uint nd[4]; u64 rv[4];
#pragma unroll
        for (int e = 0; e < 4; e++) {
          ra[e] = slotb + tid * 4 + e;
          nd[e] = (t > 0) ? (uint)t : 0u;
        }
        poll_recs<4>(ra, nd, rv);
        if (t > 0) {
          // decode: producer thread == my (w,lane); e = ut*2 + j
          f16* dst = hb + (t & 1) * 4224;
#pragma unroll
          for (int e = 0; e < 4; e++) {
            uint pay = (uint)rv[e];
            int col = 128 * pbb + 32 * w + 16 * (e >> 1) + l16;
            int r0 = quad * 4 + 2 * (e & 1);
            dst[r0 * 264 + col]       = __builtin_bit_cast(f16, (ushort)pay);
            dst[(r0 + 1) * 264 + col] = __builtin_bit_cast(f16, (ushort)(pay >> 16));
          }
        }
      }
      LBAR();
      f16x8 af[8];
#pragma unroll
      for (int kf = 0; kf < 8; kf++)
        af[kf] = *(const f16x8*)&hb[(t & 1) * 4224 + l16 * 264 + kf * 32 + quad * 8];
      f32x4 z[2][4];
#pragma unroll
      for (int ut = 0; ut < 2; ut++)
#pragma unroll
        for (int gm = 0; gm < 4; gm++) z[ut][gm] = (f32x4){0.f, 0.f, 0.f, 0.f};
#pragma unroll
      for (int kf = 0; kf < 8; kf++)
#pragma unroll
        for (int ut = 0; ut < 2; ut++)
#pragma unroll
          for (int gm = 0; gm < 4; gm++) {
            f16x8 bf = (kf < 6)
                ? wr[ut][gm][kf]
                : wl8[(w * 16 + ut * 8 + gm * 2 + (kf - 6)) * 64 + lane];
            z[ut][gm] = MFMA16(af[kf], bf, z[ut][gm]);
          }
      f16* wbuf = hb + ((t + 1) & 1) * 4224;
      u64 tg = ((u64)(uint)(t + 1)) << 32;
#pragma unroll
      for (int ut = 0; ut < 2; ut++) {
        const int myu = 128 * bb + 32 * w + 16 * ut + l16;
        u64 xs[4];
#pragma unroll
        for (int gm = 0; gm < 4; gm++)
          xs[gm] = ((u64)xv[ut][gm].y << 32) | xv[ut][gm].x;
        ushort hs[4];
#pragma unroll
        for (int r = 0; r < 4; r++) {
          float gi = sigm(z[ut][0][r] + h2f((ushort)(xs[0] >> (16 * r))));
          float ff = sigm(z[ut][1][r] + h2f((ushort)(xs[1] >> (16 * r))));
          float gg = reluf(z[ut][2][r] + h2f((ushort)(xs[2] >> (16 * r))));
          float oo = sigm(z[ut][3][r] + h2f((ushort)(xs[3] >> (16 * r))));
          c0[ut][r] = ff * c0[ut][r] + gi * gg;
          hs[r] = f2h(oo * reluf(c0[ut][r]));
          wbuf[(quad * 4 + r) * 264 + myu] = __builtin_bit_cast(f16, hs[r]);
        }
        u64* wb = ringg + (size_t)(t & 7) * 2048 + bb * 1024 + tid * 4 + ut * 2;
        str64(wb,     tg | (u64)((uint)hs[0] | ((uint)hs[1] << 16)));
        str64(wb + 1, tg | (u64)((uint)hs[2] | ((uint)hs[3] << 16)));
      }
      LBAR();
    }
  } else if (role < 4) {
    // ============ paragraph L1: 2 blocks, 64 units each, gate-complete ======
    // wave w owns units 16*(bn*4+w)..+15, ALL 4 gates (no zL bounce).
    // W1 (32 frags) + U1 (16 frags) fully in VGPRs.
    const int bn = role - 2, pbn = bn ^ 1;
    f16* h0c = (f16*)smem;                      // [16*264] 8448B
    f16* h1b = (f16*)(smem + 8448);             // [2][16*136] 8704B
    f16x8 wrA[4][8], wrB[4][4];
    {
      const f16x8* W1f8 = (const f16x8*)A.W1f;
      const f16x8* U1f8 = (const f16x8*)A.U1f;
#pragma unroll
      for (int gm = 0; gm < 4; gm++) {
#pragma unroll
        for (int kf = 0; kf < 8; kf++)
          wrA[gm][kf] = W1f8[((gm * 8 + bn * 4 + w) * 8 + kf) * 64 + lane];
#pragma unroll
        for (int kf = 0; kf < 4; kf++)
          wrB[gm][kf] = U1f8[((gm * 8 + bn * 4 + w) * 4 + kf) * 64 + lane];
      }
    }
    for (int idx = tid; idx < 4352; idx += 256) h1b[idx] = (f16)0.f;
    float c1[4] = {};
    const int un = (bn * 4 + w) * 16 + l16;     // global L1 unit 0..127
    float bth[4];
#pragma unroll
    for (int gm = 0; gm < 4; gm++) bth[gm] = A.pl1_b[gm * 128 + un];
    u64* h0rg = A.h0r + (size_t)g * 16384;
    u64* h1rg = A.h1r + (size_t)g * 8192;
    uint* bpp = A.cnt + (4 * 8 + g) * 16;       // L2 consumption
    __syncthreads();

    for (int t = 0; t < 512; t++) {
      poll_all(bpp, t > 4 ? (uint)(t - 4) : 0u, (lane == 0) && ((t & 3) == 0));
      const u64* ra[10]; uint nd[10]; u64 rv[10];
      {
        const u64* s0b = h0rg + (size_t)(t & 7) * 2048;
#pragma unroll
        for (int e = 0; e < 8; e++) { ra[e] = s0b + tid + 256 * e; nd[e] = (uint)(t + 1); }
        const u64* s1b = h1rg + (size_t)((t + 7) & 7) * 1024 + pbn * 512;
#pragma unroll
        for (int j2 = 0; j2 < 2; j2++) {
          ra[8 + j2] = s1b + tid * 2 + j2;
          nd[8 + j2] = (t > 0) ? (uint)t : 0u;
        }
      }
      poll_recs<10>(ra, nd, rv);
      {
        // h0 scatter: decode rec idx -> (bb, w_p, lane_p, ut, j)
#pragma unroll
        for (int e = 0; e < 8; e++) {
          int idx = tid + 256 * e;
          int bbp = idx >> 10, ib = idx & 1023;
          int lane_lin = ib >> 2, rr = ib & 3;
          int wp = lane_lin >> 6, lp = lane_lin & 63;
          int col = 128 * bbp + 32 * wp + 16 * (rr >> 1) + (lp & 15);
          int r0 = (lp >> 4) * 4 + 2 * (rr & 1);
          uint pay = (uint)rv[e];
          h0c[r0 * 264 + col]       = __builtin_bit_cast(f16, (ushort)pay);
          h0c[(r0 + 1) * 264 + col] = __builtin_bit_cast(f16, (ushort)(pay >> 16));
        }
        if (t > 0) {
          f16* dst = h1b + (t & 1) * 2176;
          int col = 64 * pbn + 16 * w + l16;   // producer thread == my (w,lane)
#pragma unroll
          for (int j2 = 0; j2 < 2; j2++) {
            uint pay = (uint)rv[8 + j2];
            int r0 = quad * 4 + 2 * j2;
            dst[r0 * 136 + col]       = __builtin_bit_cast(f16, (ushort)pay);
            dst[(r0 + 1) * 136 + col] = __builtin_bit_cast(f16, (ushort)(pay >> 16));
          }
        }
      }
      LBAR();
      if (tid == 0) STRLX(mytag, (uint)(t + 1));   // h0 slot consumed (L0 bp)
      f16x8 af0[8], af1[4];
#pragma unroll
      for (int kf = 0; kf < 8; kf++)
        af0[kf] = *(const f16x8*)&h0c[l16 * 264 + kf * 32 + quad * 8];
#pragma unroll
      for (int kf = 0; kf < 4; kf++)
        af1[kf] = *(const f16x8*)&h1b[(t & 1) * 2176 + l16 * 136 + kf * 32 + quad * 8];
      f32x4 z[4];
#pragma unroll
      for (int gm = 0; gm < 4; gm++) z[gm] = (f32x4){0.f, 0.f, 0.f, 0.f};
#pragma unroll
      for (int kf = 0; kf < 8; kf++)
#pragma unroll
        for (int gm = 0; gm < 4; gm++) z[gm] = MFMA16(af0[kf], wrA[gm][kf], z[gm]);
#pragma unroll
      for (int kf = 0; kf < 4; kf++)
#pragma unroll
        for (int gm = 0; gm < 4; gm++) z[gm] = MFMA16(af1[kf], wrB[gm][kf], z[gm]);
      f16* h1W = h1b + ((t + 1) & 1) * 2176;
      ushort hs[4];
#pragma unroll
      for (int r = 0; r < 4; r++) {
        float gi = sigm(z[0][r] + bth[0]);
        float ff = sigm(z[1][r] + bth[1]);
        float gg = reluf(z[2][r] + bth[2]);
        float oo = sigm(z[3][r] + bth[3]);
        c1[r] = ff * c1[r] + gi * gg;
        hs[r] = f2h(oo * reluf(c1[r]));
        h1W[(quad * 4 + r) * 136 + un] = __builtin_bit_cast(f16, hs[r]);
      }
      {
        u64 tg = ((u64)(uint)(t + 1)) << 32;
        u64* wb = h1rg + (size_t)(t & 7) * 1024 + bn * 512 + tid * 2;
        str64(wb,     tg | (u64)((uint)hs[0] | ((uint)hs[1] << 16)));
        str64(wb + 1, tg | (u64)((uint)hs[2] | ((uint)hs[3] << 16)));
      }
      LBAR();
    }
  } else if (role == 4) {
    // ============ paragraph L2 + dense tail =================================
    f16* wlds = (f16*)smem;                  // W2 @0 (4096 f16x8), U2 @4096
    f16* h1c  = (f16*)(smem + 98304);        // [2][16*136]
    f16* h2db = (f16*)(smem + 107008);       // [2][16*72]
    {
      const uint4* W2q = (const uint4*)A.W2f;
      const uint4* U2q = (const uint4*)A.U2f;
      uint4* wq = (uint4*)wlds;
      for (int idx = tid; idx < 4096; idx += 256) wq[idx] = W2q[idx];
      for (int idx = tid; idx < 2048; idx += 256) wq[4096 + idx] = U2q[idx];
    }
    for (int idx = tid; idx < 1152; idx += 256) h2db[idx] = (f16)0.f;
    float c2[4] = {0.f, 0.f, 0.f, 0.f};
    float b2[4];
#pragma unroll
    for (int gm = 0; gm < 4; gm++) b2[gm] = A.pl2_b[gm * 64 + 16 * w + l16];
    u64* h1rg = A.h1r + (size_t)g * 8192;
    const f16x8* wv8 = (const f16x8*)wlds;
    __syncthreads();

    for (int t = 0; t < 512; t++) {
      const u64* ra[4]; uint nd[4]; u64 rv[4];
      {
        const u64* s1b = h1rg + (size_t)(t & 7) * 1024;
#pragma unroll
        for (int e = 0; e < 4; e++) { ra[e] = s1b + tid + 256 * e; nd[e] = (uint)(t + 1); }
      }
      poll_recs<4>(ra, nd, rv);
      {
        f16* dst = h1c + (t & 1) * 2176;
#pragma unroll
        for (int e = 0; e < 4; e++) {
          int idx = tid + 256 * e;
          int bnp = idx >> 9, ib = idx & 511;
          int lane_lin = ib >> 1, j = ib & 1;
          int wp = lane_lin >> 6, lp = lane_lin & 63;
          int col = 64 * bnp + 16 * wp + (lp & 15);
          int r0 = (lp >> 4) * 4 + 2 * j;
          uint pay = (uint)rv[e];
          dst[r0 * 136 + col]       = __builtin_bit_cast(f16, (ushort)pay);
          dst[(r0 + 1) * 136 + col] = __builtin_bit_cast(f16, (ushort)(pay >> 16));
        }
      }
      LBAR();
      if (tid == 0) STRLX(mytag, (uint)(t + 1));    // consumption signal (bp)
      f16x8 af0[4], af1[2];
#pragma unroll
      for (int kf = 0; kf < 4; kf++)
        af0[kf] = *(const f16x8*)&h1c[(t & 1) * 2176 + l16 * 136 + kf * 32 + quad * 8];
#pragma unroll
      for (int kf = 0; kf < 2; kf++)
        af1[kf] = *(const f16x8*)&h2db[(t & 1) * 1152 + l16 * 72 + kf * 32 + quad * 8];
      f32x4 z[4];
#pragma unroll
      for (int gm = 0; gm < 4; gm++) {
        f32x4 zz = {0.f, 0.f, 0.f, 0.f};
#pragma unroll
        for (int kf = 0; kf < 4; kf++)
          zz = MFMA16(af0[kf], wv8[((gm * 4 + w) * 4 + kf) * 64 + lane], zz);
#pragma unroll
        for (int kf = 0; kf < 2; kf++)
          zz = MFMA16(af1[kf], wv8[4096 + ((gm * 4 + w) * 2 + kf) * 64 + lane], zz);
        z[gm] = zz;
      }
#pragma unroll
      for (int r = 0; r < 4; r++) {
        float gi = sigm(z[0][r] + b2[0]);
        float ff = sigm(z[1][r] + b2[1]);
        float gg = reluf(z[2][r] + b2[2]);
        float oo = sigm(z[3][r] + b2[3]);
        c2[r] = ff * c2[r] + gi * gg;
        h2db[((t + 1) & 1) * 1152 + (quad * 4 + r) * 72 + 16 * w + l16] = (f16)(oo * reluf(c2[r]));
      }
    }
    __syncthreads();
    // dense tail -> feat cols 32..63
    float* zmA = (float*)smem;                // 16*132
    float* zmB = (float*)(smem + 8448);       // 16*68
    const f16* hf = h2db;                     // parity 0
#pragma unroll 1
    for (int e = 0; e < 8; e++) {
      const int idx = tid + 256 * e, sq = idx >> 7, j = idx & 127;
      float a = A.pd0b[j];
      for (int k = 0; k < 64; k++) a += (float)hf[sq * 72 + k] * A.pd0W[k * 128 + j];
      zmA[sq * 132 + j] = reluf(a);
    }
    __syncthreads();
#pragma unroll 1
    for (int e = 0; e < 4; e++) {
      const int idx = tid + 256 * e, sq = idx >> 6, j = idx & 63;
      float a = A.pd1b[j];
      for (int k = 0; k < 128; k++) a += zmA[sq * 132 + k] * A.pd1W[k * 64 + j];
      zmB[sq * 68 + j] = reluf(a);
    }
    __syncthreads();
#pragma unroll 1
    for (int e = 0; e < 2; e++) {
      const int idx = tid + 256 * e, sq = idx >> 5, j = idx & 31;
      float a = A.pd2b[j];
      for (int k = 0; k < 64; k++) a += zmB[sq * 68 + k] * A.pd2W[k * 32 + j];
      A.feat[(g * 16 + sq) * 64 + 32 + j] = a;
    }
  } else if (role == 5) {
    // ============ title L0: ONE block, intra-CU recurrence (no ring) ========
    // wave w owns unit-tiles {2w, 2w+1} (32 units), all gates. Weights 128KB LDS.
    f16* wlds = (f16*)smem;                     // 128KB, direct copy of U0tf
    f16* hb   = (f16*)(smem + 131072);          // [2][16*136]
    {
      const uint4* U0tq = (const uint4*)A.U0tf;
      uint4* wq = (uint4*)wlds;
      for (int idx = tid; idx < 8192; idx += 256) wq[idx] = U0tq[idx];
    }
    for (int idx = tid; idx < 4352; idx += 256) hb[idx] = (f16)0.f;
    float c0[2][4] = {};
    u64* ringg = A.h0tr + (size_t)g * 8192;
    const uint2* xq2 = (const uint2*)A.xt2;
    const f16x8* wv8 = (const f16x8*)wlds;
    uint* bpp = A.cnt + (6 * 8 + g) * 16;       // tL1 consumption
    __syncthreads();

    for (int t = 0; t < 64; t++) {
      uint2 xv[2][4];
#pragma unroll
      for (int ut = 0; ut < 2; ut++) {
        const int myu = 32 * w + 16 * ut + l16;
        size_t xb = ((size_t)(g * 64 + t) * 4) * 512 + (size_t)myu * 4 + quad;
#pragma unroll
        for (int gm = 0; gm < 4; gm++) xv[ut][gm] = xq2[xb + (size_t)gm * 512];
      }
      poll_all(bpp, t > 4 ? (uint)(t - 4) : 0u,
               (lane == 0) && (t > 0) && ((t & 3) == 0));
      f16x8 af[4];
#pragma unroll
      for (int kf = 0; kf < 4; kf++)
        af[kf] = *(const f16x8*)&hb[(t & 1) * 2176 + l16 * 136 + kf * 32 + quad * 8];
      f32x4 z[2][4];
#pragma unroll
      for (int ut = 0; ut < 2; ut++)
#pragma unroll
        for (int gm = 0; gm < 4; gm++) z[ut][gm] = (f32x4){0.f, 0.f, 0.f, 0.f};
#pragma unroll
      for (int kf = 0; kf < 4; kf++)
#pragma unroll
        for (int ut = 0; ut < 2; ut++)
#pragma unroll
          for (int gm = 0; gm < 4; gm++)
            z[ut][gm] = MFMA16(af[kf],
                wv8[((gm * 8 + w * 2 + ut) * 4 + kf) * 64 + lane], z[ut][gm]);
      f16* wbuf = hb + ((t + 1) & 1) * 2176;
      u64 tg = ((u64)(uint)(t + 1)) << 32;
#pragma unroll
      for (int ut = 0; ut < 2; ut++) {
        const int myu = 32 * w + 16 * ut + l16;
        u64 xs[4];
#pragma unroll
        for (int gm = 0; gm < 4; gm++)
          xs[gm] = ((u64)xv[ut][gm].y << 32) | xv[ut][gm].x;
        ushort hs[4];
#pragma unroll
        for (int r = 0; r < 4; r++) {
          float gi = sigm(z[ut][0][r] + h2f((ushort)(xs[0] >> (16 * r))));
          float ff = sigm(z[ut][1][r] + h2f((ushort)(xs[1] >> (16 * r))));
          float gg = reluf(z[ut][2][r] + h2f((ushort)(xs[2] >> (16 * r))));
          float oo = sigm(z[ut][3][r] + h2f((ushort)(xs[3] >> (16 * r))));
          c0[ut][r] = ff * c0[ut][r] + gi * gg;
          hs[r] = f2h(oo * reluf(c0[ut][r]));
          wbuf[(quad * 4 + r) * 136 + myu] = __builtin_bit_cast(f16, hs[r]);
        }
        u64* wb = ringg + (size_t)(t & 7) * 1024 + tid * 4 + ut * 2;
        str64(wb,     tg | (u64)((uint)hs[0] | ((uint)hs[1] << 16)));
        str64(wb + 1, tg | (u64)((uint)hs[2] | ((uint)hs[3] << 16)));
      }
      LBAR();
    }
  } else {
    // ============ title L1 + dense tail =====================================
    f16* wlds = (f16*)smem;                  // W1t @0, U1t @4096 (f16x8 units)
    f16* h0tc = (f16*)(smem + 98304);        // [2][16*136]
    f16* h1db = (f16*)(smem + 107008);       // [2][16*72]
    {
      const uint4* W1tq = (const uint4*)A.W1tf;
      const uint4* U1tq = (const uint4*)A.U1tf;
      uint4* wq = (uint4*)wlds;
      for (int idx = tid; idx < 4096; idx += 256) wq[idx] = W1tq[idx];
      for (int idx = tid; idx < 2048; idx += 256) wq[4096 + idx] = U1tq[idx];
    }
    for (int idx = tid; idx < 1152; idx += 256) h1db[idx] = (f16)0.f;
    float c1[4] = {0.f, 0.f, 0.f, 0.f};
    float bt[4];
#pragma unroll
    for (int gm = 0; gm < 4; gm++) bt[gm] = A.tl1_b[gm * 64 + 16 * w + l16];
    u64* ringg = A.h0tr + (size_t)g * 8192;
    const f16x8* wv8 = (const f16x8*)wlds;
    __syncthreads();

    for (int t = 0; t < 64; t++) {
      const u64* ra[4]; uint nd[4]; u64 rv[4];
      {
        const u64* base = ringg + (size_t)(t & 7) * 1024;
#pragma unroll
        for (int e = 0; e < 4; e++) { ra[e] = base + tid * 4 + e; nd[e] = (uint)(t + 1); }
      }
      poll_recs<4>(ra, nd, rv);
      {
        // decode: producer thread == my (w,lane); e = ut*2 + j
        f16* dst = h0tc + (t & 1) * 2176;
#pragma unroll
        for (int e = 0; e < 4; e++) {
          uint pay = (uint)rv[e];
          int col = 32 * w + 16 * (e >> 1) + l16;
          int r0 = quad * 4 + 2 * (e & 1);
          dst[r0 * 136 + col]       = __builtin_bit_cast(f16, (ushort)pay);
          dst[(r0 + 1) * 136 + col] = __builtin_bit_cast(f16, (ushort)(pay >> 16));
        }
      }
      LBAR();
      if (tid == 0) STRLX(mytag, (uint)(t + 1));    // consumption signal (bp)
      f16x8 af0[4], af1[2];
#pragma unroll
      for (int kf = 0; kf < 4; kf++)
        af0[kf] = *(const f16x8*)&h0tc[(t & 1) * 2176 + l16 * 136 + kf * 32 + quad * 8];
#pragma unroll
      for (int kf = 0; kf < 2; kf++)
        af1[kf] = *(const f16x8*)&h1db[(t & 1) * 1152 + l16 * 72 + kf * 32 + quad * 8];
      f32x4 z[4];
#pragma unroll
      for (int gm = 0; gm < 4; gm++) {
        f32x4 zz = {0.f, 0.f, 0.f, 0.f};
#pragma unroll
        for (int kf = 0; kf < 4; kf++)
          zz = MFMA16(af0[kf], wv8[((gm * 4 + w) * 4 + kf) * 64 + lane], zz);
#pragma unroll
        for (int kf = 0; kf < 2; kf++)
          zz = MFMA16(af1[kf], wv8[4096 + ((gm * 4 + w) * 2 + kf) * 64 + lane], zz);
        z[gm] = zz;
      }
#pragma unroll
      for (int r = 0; r < 4; r++) {
        float gi = sigm(z[0][r] + bt[0]);
        float ff = sigm(z[1][r] + bt[1]);
        float gg = reluf(z[2][r] + bt[2]);
        float oo = sigm(z[3][r] + bt[3]);
        c1[r] = ff * c1[r] + gi * gg;
        h1db[((t + 1) & 1) * 1152 + (quad * 4 + r) * 72 + 16 * w + l16] = (f16)(oo * reluf(c1[r]));
      }
    }
    __syncthreads();
    // dense tail -> feat cols 0..31
    float* zmA = (float*)smem;
    float* zmB = (float*)(smem + 8448);
    const f16* hf = h1db;                    // parity 0
#pragma unroll 1
    for (int e = 0; e < 8; e++) {
      const int idx = tid + 256 * e, sq = idx >> 7, j = idx & 127;
      float a = A.td0b[j];
      for (int k = 0; k < 64; k++) a += (float)hf[sq * 72 + k] * A.td0W[k * 128 + j];
      zmA[sq * 132 + j] = reluf(a);
    }
    __syncthreads();
#pragma unroll 1
    for (int e = 0; e < 4; e++) {
      const int idx = tid + 256 * e, sq = idx >> 6, j = idx & 63;
      float a = A.td1b[j];
      for (int k = 0; k < 128; k++) a += zmA[sq * 132 + k] * A.td1W[k * 64 + j];
      zmB[sq * 68 + j] = reluf(a);
    }
    __syncthreads();
#pragma unroll 1
    for (int e = 0; e < 2; e++) {
      const int idx = tid + 256 * e, sq = idx >> 5, j = idx & 31;
      float a = A.td2b[j];
      for (int k = 0; k < 64; k++) a += zmB[sq * 68 + k] * A.td2W[k * 32 + j];
      A.feat[(g * 16 + sq) * 64 + j] = a;
    }
  }
}

// ---------------- head
__global__ __launch_bounds__(256) void head_kernel(const float* __restrict__ feat,
    const float* __restrict__ L0W, const float* __restrict__ L0b,
    const float* __restrict__ L1W, const float* __restrict__ L1b,
    const float* __restrict__ L2W, const float* __restrict__ L2b,
    const float* __restrict__ L3W, const float* __restrict__ L3b,
    float* __restrict__ out) {
  __shared__ float xb[512];
  __shared__ float y0[2048];
  __shared__ float y1[1024];
  __shared__ float y2[512];
  const int tid = threadIdx.x;
  for (int idx = tid; idx < 512; idx += 256) {
    int b = idx >> 6, d = idx & 63;
    float s = 0.f;
    for (int n = 0; n < 16; n++) s += feat[(b * 16 + n) * 64 + d];
    xb[idx] = s * (1.f / 16.f);
  }
  __syncthreads();
  for (int idx = tid; idx < 2048; idx += 256) {
    int b = idx >> 8, j = idx & 255;
    float a = L0b[j];
    for (int k = 0; k < 64; k++) a += xb[b * 64 + k] * L0W[k * 256 + j];
    y0[idx] = reluf(a);
  }
  __syncthreads();
  for (int idx = tid; idx < 1024; idx += 256) {
    int b = idx >> 7, j = idx & 127;
    float a = L1b[j];
    for (int k = 0; k < 256; k++) a += y0[b * 256 + k] * L1W[k * 128 + j];
    y1[idx] = reluf(a);
  }
  __syncthreads();
  for (int idx = tid; idx < 512; idx += 256) {
    int b = idx >> 6, j = idx & 63;
    float a = L2b[j];
    for (int k = 0; k < 128; k++) a += y1[b * 128 + k] * L2W[k * 64 + j];
    y2[idx] = reluf(a);
  }
  __syncthreads();
  {
    int b = tid >> 5, j = tid & 31;
    float a = L3b[j];
    for (int k = 0; k < 64; k++) a += y2[b * 64 + k] * L3W[k * 32 + j];
    out[b * 32 + j] = 1.f / (1.f + __expf(-a));
  }
}

extern "C" void kernel_launch(void* const* d_in, const int* in_sizes, int n_in,
                              void* d_out, int out_size, void* d_ws, size_t ws_size,
                              hipStream_t stream) {
  const int*   t_tok = (const int*)d_in[0];
  const int*   p_tok = (const int*)d_in[1];
  const float* emb_t = (const float*)d_in[2];
  const float* emb_p = (const float*)d_in[3];
  const float* tl0_W = (const float*)d_in[4];
  const float* tl0_U = (const float*)d_in[5];
  const float* tl0_b = (const float*)d_in[6];
  const float* tl1_W = (const float*)d_in[7];
  const float* tl1_U = (const float*)d_in[8];
  const float* tl1_b = (const float*)d_in[9];
  const float* td0_W = (const float*)d_in[10];
  const float* td0_b = (const float*)d_in[11];
  const float* td1_W = (const float*)d_in[12];
  const float* td1_b = (const float*)d_in[13];
  const float* td2_W = (const float*)d_in[14];
  const float* td2_b = (const float*)d_in[15];
  const float* pl0_W = (const float*)d_in[16];
  const float* pl0_U = (const float*)d_in[17];
  const float* pl0_b = (const float*)d_in[18];
  const float* pl1_W = (const float*)d_in[19];
  const float* pl1_U = (const float*)d_in[20];
  const float* pl1_b = (const float*)d_in[21];
  const float* pl2_W = (const float*)d_in[22];
  const float* pl2_U = (const float*)d_in[23];
  const float* pl2_b = (const float*)d_in[24];
  const float* pd0_W = (const float*)d_in[25];
  const float* pd0_b = (const float*)d_in[26];
  const float* pd1_W = (const float*)d_in[27];
  const float* pd1_b = (const float*)d_in[28];
  const float* pd2_W = (const float*)d_in[29];
  const float* pd2_b = (const float*)d_in[30];
  const float* L0_W  = (const float*)d_in[31];
  const float* L0_b  = (const float*)d_in[32];
  const float* L1_W  = (const float*)d_in[33];
  const float* L1_b  = (const float*)d_in[34];
  const float* L2_W  = (const float*)d_in[35];
  const float* L2_b  = (const float*)d_in[36];
  const float* L3_W  = (const float*)d_in[37];
  const float* L3_b  = (const float*)d_in[38];

  char* ws = (char*)d_ws;
  size_t off = 0;
  auto alloc = [&](size_t bytes) {
    void* ptr = ws + off;
    off += (bytes + 255) & ~(size_t)255;
    return ptr;
  };
  f16* xp2  = (f16*)alloc((size_t)8 * 512 * 4 * 4096 * 2);     // 128 MB
  f16* xt2  = (f16*)alloc((size_t)8 * 64 * 4 * 2048 * 2);      // 8 MB
  f16* Bp   = (f16*)alloc((size_t)256 * 1024 * 2);
  f16* Bt   = (f16*)alloc((size_t)128 * 512 * 2);
  f16* U0f  = (f16*)alloc((size_t)256 * 1024 * 2);
  f16* W1f  = (f16*)alloc((size_t)256 * 512 * 2);
  f16* U1f  = (f16*)alloc((size_t)128 * 512 * 2);
  f16* W2f  = (f16*)alloc((size_t)128 * 256 * 2);
  f16* U2f  = (f16*)alloc((size_t)64 * 256 * 2);
  f16* U0tf = (f16*)alloc((size_t)128 * 512 * 2);
  f16* W1tf = (f16*)alloc((size_t)128 * 256 * 2);
  f16* U1tf = (f16*)alloc((size_t)64 * 256 * 2);
  size_t ringoff = off;
  u64* h0r  = (u64*)alloc((size_t)8 * 16384 * 8);              // 1 MB
  u64* h1r  = (u64*)alloc((size_t)8 * 8192 * 8);               // 512 KB
  u64* h0tr = (u64*)alloc((size_t)8 * 8192 * 8);               // 512 KB
  uint* cnt = (uint*)alloc((size_t)96 * 16 * 4);
  size_t ringlen = off - ringoff;
  float* feat = (float*)alloc((size_t)128 * 64 * 4);

  // rings + cnt MUST be zeroed every replay: stale record tags from a prior
  // replay would false-validate the tag-in-data protocol.
  hipMemsetAsync(ws + ringoff, 0, ringlen, stream);

  pack_bsw<8><<<1024, 256, 0, stream>>>(pl0_W, Bp, 1024);
  pack_bsw<4><<<256, 256, 0, stream>>>(tl0_W, Bt, 512);
  pack_bsw<8><<<1024, 256, 0, stream>>>(pl0_U, U0f, 1024);
  pack_bsw<8><<<512, 256, 0, stream>>>(pl1_W, W1f, 512);
  pack_bsw<4><<<256, 256, 0, stream>>>(pl1_U, U1f, 512);
  pack_bsw<4><<<128, 256, 0, stream>>>(pl2_W, W2f, 256);
  pack_bsw<2><<<64, 256, 0, stream>>>(pl2_U, U2f, 256);
  pack_bsw<4><<<256, 256, 0, stream>>>(tl0_U, U0tf, 512);
  pack_bsw<4><<<128, 256, 0, stream>>>(tl1_W, W1tf, 256);
  pack_bsw<2><<<64, 256, 0, stream>>>(tl1_U, U1tf, 256);
  gemm_xw<512, 256, 8, 1024, 64, 0><<<1024, 256, 0, stream>>>(p_tok, emb_p, Bp, pl0_b, xp2);
  gemm_xw<64, 128, 4, 512, 32, 1><<<128, 256, 0, stream>>>(t_tok, emb_t, Bt, tl0_b, xt2);

  RP ra;
  ra.xp2 = xp2; ra.xt2 = xt2;
  ra.U0f = U0f; ra.W1f = W1f; ra.U1f = U1f; ra.W2f = W2f; ra.U2f = U2f;
  ra.U0tf = U0tf; ra.W1tf = W1tf; ra.U1tf = U1tf;
  ra.pl1_b = pl1_b; ra.pl2_b = pl2_b; ra.tl1_b = tl1_b;
  ra.pd0W = pd0_W; ra.pd0b = pd0_b; ra.pd1W = pd1_W; ra.pd1b = pd1_b;
  ra.pd2W = pd2_W; ra.pd2b = pd2_b;
  ra.td0W = td0_W; ra.td0b = td0_b; ra.td1W = td1_W; ra.td1b = td1_b;
  ra.td2W = td2_W; ra.td2b = td2_b;
  ra.h0r = h0r; ra.h1r = h1r; ra.h0tr = h0tr; ra.cnt = cnt;
  ra.feat = feat;
  recur_pipe<<<56, 256, 0, stream>>>(ra);

  head_kernel<<<1, 256, 0, stream>>>(feat, L0_W, L0_b, L1_W, L1_b, L2_W, L2_b,
                                     L3_W, L3_b, (float*)d_out);
}

// Round 8
// 1408.559 us; speedup vs baseline: 1.3958x; 1.3958x over previous
//
#include <hip/hip_runtime.h>
#include <hip/hip_fp16.h>

typedef _Float16 f16;
typedef _Float16 f16x8 __attribute__((ext_vector_type(8)));
typedef float    f32x4 __attribute__((ext_vector_type(4)));
typedef unsigned short ushort;
typedef unsigned int uint;
typedef unsigned long long u64;

__device__ __forceinline__ float sigm(float x) { return 1.f / (1.f + __expf(-x)); }
__device__ __forceinline__ float reluf(float x) { return x > 0.f ? x : 0.f; }
__device__ __forceinline__ float h2f(ushort u) { return (float)__builtin_bit_cast(f16, u); }
__device__ __forceinline__ ushort f2h(float v) { return __builtin_bit_cast(ushort, (f16)v); }

#define LDRLX(p)    __hip_atomic_load((p), __ATOMIC_RELAXED, __HIP_MEMORY_SCOPE_AGENT)
#define STRLX(p, v) __hip_atomic_store((p), (v), __ATOMIC_RELAXED, __HIP_MEMORY_SCOPE_AGENT)
#define MFMA16(a, b, c) __builtin_amdgcn_mfma_f32_16x16x32_f16((a), (b), (c), 0, 0, 0)
// lgkm-only barrier: orders LDS without draining vmcnt (ring publishes stay in
// flight across step barriers; correctness = tag-in-data + backpressure).
#define LBAR() do { asm volatile("s_waitcnt lgkmcnt(0)" ::: "memory"); \
                    __builtin_amdgcn_s_barrier(); } while (0)

// Backpressure / flag poll (agent scope; amortized off critical path).
__device__ __forceinline__ void poll_all(uint* p, uint need, bool act) {
  bool done = !act;
  while (true) {
    if (!done) done = (LDRLX(p) >= need);
    if (__all((int)done)) break;
    __builtin_amdgcn_s_sleep(1);
  }
}

__device__ __forceinline__ u64 ldr64(const u64* p) {
  return __hip_atomic_load(p, __ATOMIC_RELAXED, __HIP_MEMORY_SCOPE_AGENT);
}
__device__ __forceinline__ void str64(u64* p, u64 v) {
  __hip_atomic_store(p, v, __ATOMIC_RELAXED, __HIP_MEMORY_SCOPE_AGENT);
}

// Tag-in-data record poll: each u64 record = {tag:32 | payload(2xf16):32}.
template <int NR>
__device__ __forceinline__ void poll_recs(const u64* const (&ra)[NR],
                                          const uint (&nd)[NR], u64 (&rv)[NR]) {
  bool ok[NR];
#pragma unroll
  for (int i = 0; i < NR; i++) ok[i] = (nd[i] == 0u);
  while (true) {
    bool all = true;
#pragma unroll
    for (int i = 0; i < NR; i++) if (!ok[i]) rv[i] = ldr64(ra[i]);
#pragma unroll
    for (int i = 0; i < NR; i++) if (!ok[i]) ok[i] = ((uint)(rv[i] >> 32) >= nd[i]);
#pragma unroll
    for (int i = 0; i < NR; i++) all &= ok[i];
    if (all) return;
    __builtin_amdgcn_s_sleep(1);
  }
}

// ---------------- pack B for MFMA b-frag layout (validated R1-R6)
template <int KF>
__global__ void pack_bsw(const float* __restrict__ B, f16* __restrict__ dst, int N) {
  int id = blockIdx.x * 256 + threadIdx.x;
  int total = KF * 32 * N;
  if (id >= total) return;
  int j  = id & 7;
  int L  = (id >> 3) & 63;
  int r  = id >> 9;
  int kf = r & (KF - 1);
  int c  = r / KF;
  int k  = kf * 32 + ((L >> 4) * 8) + j;
  int n  = c * 16 + (L & 15);
  dst[id] = (f16)B[k * N + n];
}

struct RP {
  const int *t_tok, *p_tok;
  const float *emb_t, *emb_p;
  const f16 *Bp, *Bt;
  const float *tl0_b, *pl0_b;
  f16 *xp2, *xt2;
  const f16 *U0f, *W1f, *U1f, *W2f, *U2f, *U0tf, *W1tf, *U1tf;
  const float *pl1_b, *pl2_b, *tl1_b;
  const float *pd0W, *pd0b, *pd1W, *pd1b, *pd2W, *pd2b;
  const float *td0W, *td0b, *td1W, *td1b, *td2W, *td2b;
  u64 *h0r, *h1r, *h0tr;
  uint *cnt, *xfl, *tfl;
  float* feat;
};

// ---------------- worker xW GEMM tile (R6 gemm_xw body; X stores are
// AGENT-SCOPE u64 so consumers on other XCDs see them without kernel-boundary
// flushes; trailing __syncthreads drains vmcnt before the caller's flag store).
template <int Sx, int K, int KF, int N, int NC, int MODE>
__device__ __forceinline__ void gemm_tile(int g, int t0,
    const int* __restrict__ tok, const float* __restrict__ emb,
    const f16* __restrict__ Bsw, const float* __restrict__ bias,
    u64* __restrict__ X, char* smem) {
  int* tokLds = (int*)smem;                  // 256B
  f16x8* bLds = (f16x8*)(smem + 1024);       // 8KB max
  const int tid = threadIdx.x;
  if (tid < 64) {
    int wv = tid >> 4, rho = tid & 15;
    tokLds[tid] = tok[(g * 16 + rho) * Sx + t0 + wv];
  }
  __syncthreads();
  const int wave = tid >> 6, lane = tid & 63;
  const int quad = lane >> 4, l16 = lane & 15;
  f16x8 a[KF];
  {
    const float* arow = emb + (long)tokLds[wave * 16 + l16] * K + quad * 8;
#pragma unroll
    for (int kf = 0; kf < KF; kf++) {
      float4 v0 = *(const float4*)(arow + kf * 32);
      float4 v1 = *(const float4*)(arow + kf * 32 + 4);
      f16x8 tv;
      tv[0] = (f16)v0.x; tv[1] = (f16)v0.y; tv[2] = (f16)v0.z; tv[3] = (f16)v0.w;
      tv[4] = (f16)v1.x; tv[5] = (f16)v1.y; tv[6] = (f16)v1.z; tv[7] = (f16)v1.w;
      a[kf] = tv;
    }
  }
  const int t = t0 + wave;
  const f16x8* Bfrag = (const f16x8*)Bsw;
  for (int c = 0; c < NC; c++) {
    __syncthreads();                         // prev iter's bLds readers done
    for (int i = tid; i < KF * 64; i += 256) bLds[i] = Bfrag[c * KF * 64 + i];
    __syncthreads();
    f32x4 acc = {0.f, 0.f, 0.f, 0.f};
#pragma unroll
    for (int kf = 0; kf < KF; kf++)
      acc = MFMA16(a[kf], bLds[kf * 64 + lane], acc);
    const int col = c * 16 + l16;
    const float bc = bias[col];
    uint lo = (uint)f2h(acc[0] + bc) | ((uint)f2h(acc[1] + bc) << 16);
    uint hi = (uint)f2h(acc[2] + bc) | ((uint)f2h(acc[3] + bc) << 16);
    u64 pv = (u64)lo | ((u64)hi << 32);
    size_t b64;
    if (MODE == 0) {
      int gm = col >> 8, u = col & 255;
      b64 = (((size_t)(g * 512 + t) * 4 + gm) * 1024) + u * 4 + quad;
    } else {
      int gm = col >> 7, u = col & 127;
      b64 = (((size_t)(g * 64 + t) * 4 + gm) * 512) + u * 4 + quad;
    }
    str64(X + b64, pv);
  }
  __syncthreads();                           // drain all waves' X stores
}

__device__ void worker_body(const RP& A, int wid, char* smem) {
  const int tid = threadIdx.x;
  // 1152 tiles ordered (tchunk, g), title first -> early timesteps first.
  for (int tile = wid; tile < 1152; tile += 160) {
    if (tile < 128) {
      int tch = tile >> 3, g = tile & 7;
      gemm_tile<64, 128, 4, 512, 32, 1>(g, tch * 4, A.t_tok, A.emb_t, A.Bt,
                                        A.tl0_b, (u64*)A.xt2, smem);
      if (tid == 0) STRLX(A.tfl + g * 16 + tch, 1u);
    } else {
      int m0 = tile - 128, tch = m0 >> 3, g = m0 & 7;
      gemm_tile<512, 256, 8, 1024, 64, 0>(g, tch * 4, A.p_tok, A.emb_p, A.Bp,
                                          A.pl0_b, (u64*)A.xp2, smem);
      if (tid == 0) STRLX(A.xfl + g * 128 + tch, 1u);
    }
  }
}

// ---------------- fused persistent kernel: 256 blocks x 256 thr.
// blk 0-95: R12/R6 recurrence (verified) — role = blk>>3, g = blk&7:
//   roles 0-3 paraL0(bb), 4-7 paraL1(bn), 8 paraL2+tail, 9-10 titleL0(bb),
//   11 titleL1+tail. blk 96-255: 160 xW-GEMM workers (tile queue + flags).
// All 256 blocks are co-resident (148KB LDS -> 1 block/CU, grid == CU count),
// so the recur<->worker dependency cannot deadlock; and workers always
// terminate, so partial residency also makes progress.
// X path is agent-scope (stores AND loads) because there is no kernel
// boundary between producer and consumer (cross-XCD L2s not coherent; graph
// replays could leave stale consumer-side lines otherwise).
// Rings/cnt/flags zeroed every replay.
__global__ __launch_bounds__(256, 1) void fused(RP A) {
  __shared__ __align__(16) char smem[147968];
  const int blk = blockIdx.x;
  if (blk >= 96) { worker_body(A, blk - 96, smem); return; }
  const int tid = threadIdx.x;
  const int w = tid >> 6, lane = tid & 63;
  const int quad = lane >> 4, l16 = lane & 15;
  const int role = blk >> 3, g = blk & 7;
  uint* mytag = A.cnt + (role * 8 + g) * 16;

  if (role < 4) {
    // ================= paragraph L0: units 64*bb.. , weights 128KB LDS =======
    const int bb = role;
    f16* wlds = (f16*)smem;                 // [gm4][wv4][kf8][64] f16x8
    f16* hb   = (f16*)(smem + 131072);      // [2][16*264]
    {
      const uint4* U0q = (const uint4*)A.U0f;
      uint4* wq = (uint4*)wlds;
      for (int idx = tid; idx < 8192; idx += 256) {
        int gm = idx >> 11, r = idx & 2047, wv = r >> 9, kf = (r >> 6) & 7, ln = r & 63;
        wq[idx] = U0q[((gm * 16 + 4 * bb + wv) * 8 + kf) * 64 + ln];
      }
    }
    for (int idx = tid; idx < 4224; idx += 256) hb[idx] = (f16)0.f;
    float c0[4] = {0.f, 0.f, 0.f, 0.f};
    u64* ringg = A.h0r + (size_t)g * 16384;
    int pp3[3]; { int q = 0; for (int p = 0; p < 4; p++) if (p != bb) pp3[q++] = p; }
    const u64* xq2 = (const u64*)A.xp2;
    const f16x8* wv8 = (const f16x8*)wlds;
    const int myu = 64 * bb + 16 * w + l16;
    const int ulq = 16 * ((tid >> 4) & 3) + (tid & 15);   // coalesced-rec decode
    const int qd  = tid >> 6;
    uint* bpp = A.cnt;
    if (lane < 4) bpp = A.cnt + ((4 + lane) * 8 + g) * 16;
    uint* xflg = A.xfl + g * 128;
    __syncthreads();

    for (int t = 0; t < 512; t++) {
      {
        uint* pp = bpp; uint need = 0; bool act = false;
        if (lane < 4) { act = (t > 0) && ((t & 3) == 0); need = t > 4 ? (uint)(t - 4) : 0u; }
        else if (lane == 4) { act = ((t & 3) == 0); need = 1u; pp = xflg + (t >> 2); }
        poll_all(pp, need, act);
      }
      u64 xs[4];
      {
        size_t xb = ((size_t)(g * 512 + t) * 4) * 1024 + (size_t)myu * 4 + quad;
#pragma unroll
        for (int gm = 0; gm < 4; gm++) xs[gm] = ldr64(xq2 + xb + (size_t)gm * 1024);
      }
      {
        const u64* slotb = ringg + (size_t)((t + 7) & 7) * 2048;
        const u64* ra[6]; uint nd[6]; u64 rv[6];
#pragma unroll
        for (int q = 0; q < 3; q++) {
          const u64* rb = slotb + pp3[q] * 512 + 2 * tid;
          ra[q * 2] = rb; ra[q * 2 + 1] = rb + 1;
          nd[q * 2] = nd[q * 2 + 1] = (t > 0) ? (uint)t : 0u;
        }
        poll_recs<6>(ra, nd, rv);
        if (t > 0) {
          f16* dst = hb + (t & 1) * 4224;
#pragma unroll
          for (int q = 0; q < 3; q++)
#pragma unroll
            for (int j = 0; j < 2; j++) {
              uint pay = (uint)rv[q * 2 + j];
              int r0 = qd * 4 + 2 * j;
              dst[r0 * 264 + pp3[q] * 64 + ulq]       = __builtin_bit_cast(f16, (ushort)pay);
              dst[(r0 + 1) * 264 + pp3[q] * 64 + ulq] = __builtin_bit_cast(f16, (ushort)(pay >> 16));
            }
        }
      }
      LBAR();
      f16x8 af[8];
#pragma unroll
      for (int kf = 0; kf < 8; kf++)
        af[kf] = *(const f16x8*)&hb[(t & 1) * 4224 + l16 * 264 + kf * 32 + quad * 8];
      f32x4 z[4];
#pragma unroll
      for (int gm = 0; gm < 4; gm++) {
        f32x4 zz = {0.f, 0.f, 0.f, 0.f};
#pragma unroll
        for (int kf = 0; kf < 8; kf++)
          zz = MFMA16(af[kf], wv8[((gm * 4 + w) * 8 + kf) * 64 + lane], zz);
        z[gm] = zz;
      }
      ushort hs[4];
      f16* wbuf = hb + ((t + 1) & 1) * 4224;
#pragma unroll
      for (int r = 0; r < 4; r++) {
        float gi = sigm(z[0][r] + h2f((ushort)(xs[0] >> (16 * r))));
        float ff = sigm(z[1][r] + h2f((ushort)(xs[1] >> (16 * r))));
        float gg = reluf(z[2][r] + h2f((ushort)(xs[2] >> (16 * r))));
        float oo = sigm(z[3][r] + h2f((ushort)(xs[3] >> (16 * r))));
        c0[r] = ff * c0[r] + gi * gg;
        hs[r] = f2h(oo * reluf(c0[r]));
        wbuf[(quad * 4 + r) * 264 + myu] = __builtin_bit_cast(f16, hs[r]);
      }
      {
        // coalesced publish: rec = bb*512 + quad*128 + w*32 + l16*2 (+j)
        u64 tg = ((u64)(uint)(t + 1)) << 32;
        u64* wb = ringg + (size_t)(t & 7) * 2048 + bb * 512 +
                  quad * 128 + w * 32 + l16 * 2;
        str64(wb,     tg | (u64)((uint)hs[0] | ((uint)hs[1] << 16)));
        str64(wb + 1, tg | (u64)((uint)hs[2] | ((uint)hs[3] << 16)));
      }
    }
  } else if (role < 8) {
    // ================= paragraph L1: units 32*bn.., 96KB LDS weights ========
    const int bn = role - 4;
    f16* wlds = (f16*)smem;                  // W1 @0 (4096 x f16x8), U1 @4096
    f16* h0c  = (f16*)(smem + 98304);        // 16*264
    f16* h1b  = (f16*)(smem + 106752);       // [2][16*136]
    float* zL = (float*)(smem + 115456);     // 16*132
    {
      const uint4* W1q = (const uint4*)A.W1f;
      const uint4* U1q = (const uint4*)A.U1f;
      uint4* wq = (uint4*)wlds;
      for (int idx = tid; idx < 4096; idx += 256) {
        int gm = idx >> 10, r = idx & 1023, j2 = r >> 9, kf = (r >> 6) & 7, ln = r & 63;
        wq[idx] = W1q[((gm * 8 + bn * 2 + j2) * 8 + kf) * 64 + ln];
      }
      for (int idx = tid; idx < 2048; idx += 256) {
        int gm = idx >> 9, r = idx & 511, j2 = r >> 8, kf = (r >> 6) & 3, ln = r & 63;
        wq[4096 + idx] = U1q[((gm * 8 + bn * 2 + j2) * 4 + kf) * 64 + ln];
      }
    }
    for (int idx = tid; idx < 2176; idx += 256) h1b[idx] = (f16)0.f;
    float c1[2] = {0.f, 0.f};
    float bth[4];
    { int un = tid & 31; for (int gm = 0; gm < 4; gm++) bth[gm] = A.pl1_b[gm * 128 + 32 * bn + un]; }
    u64* h0rg = A.h0r + (size_t)g * 16384;
    u64* h1rg = A.h1r + (size_t)g * 8192;
    int pp3[3]; { int q = 0; for (int p = 0; p < 4; p++) if (p != bn) pp3[q++] = p; }
    const f16x8* wv8 = (const f16x8*)wlds;
    uint* bpp = A.cnt + (8 * 8 + g) * 16;
    __syncthreads();

    for (int t = 0; t < 512; t++) {
      {
        bool act = (lane == 0) && ((t & 3) == 0);
        uint need = t > 4 ? (uint)(t - 4) : 0u;
        poll_all(bpp, need, act);
      }
      const u64* ra[11]; uint nd[11]; u64 rv[11];
      {
        const u64* s0b = h0rg + (size_t)(t & 7) * 2048;
#pragma unroll
        for (int e = 0; e < 8; e++) { ra[e] = s0b + tid + 256 * e; nd[e] = (uint)(t + 1); }
        const u64* s1b = h1rg + (size_t)((t + 7) & 7) * 1024;
#pragma unroll
        for (int q = 0; q < 3; q++) { ra[8 + q] = s1b + pp3[q] * 256 + tid; nd[8 + q] = (t > 0) ? (uint)t : 0u; }
      }
      poll_recs<11>(ra, nd, rv);
      {
        // h0 scatter: decode coalesced rec idx -> (bb, quad, w, l16, j)
#pragma unroll
        for (int e = 0; e < 8; e++) {
          int idx = tid + 256 * e;
          int bbq = idx >> 9, r = idx & 511;
          int jj = r & 1, l16c = (r >> 1) & 15, wc = (r >> 5) & 3, qdc = (r >> 7) & 3;
          int col = bbq * 64 + 16 * wc + l16c;
          int r0 = qdc * 4 + 2 * jj;
          uint pay = (uint)rv[e];
          h0c[r0 * 264 + col]       = __builtin_bit_cast(f16, (ushort)pay);
          h0c[(r0 + 1) * 264 + col] = __builtin_bit_cast(f16, (ushort)(pay >> 16));
        }
        if (t > 0) {
          f16* dst = h1b + (t & 1) * 2176;
          int sqc = tid >> 5, unc = tid & 31;   // rec = sq*32+un = tid
#pragma unroll
          for (int q = 0; q < 3; q++) {
            uint pay = (uint)rv[8 + q];
            dst[sqc * 136 + pp3[q] * 32 + unc]       = __builtin_bit_cast(f16, (ushort)pay);
            dst[(sqc + 8) * 136 + pp3[q] * 32 + unc] = __builtin_bit_cast(f16, (ushort)(pay >> 16));
          }
        }
      }
      LBAR();
      if (tid == 0) STRLX(mytag, (uint)(t + 1));    // consumption signal (bp)
      f16x8 af0[8], af1[4];
#pragma unroll
      for (int kf = 0; kf < 8; kf++)
        af0[kf] = *(const f16x8*)&h0c[l16 * 264 + kf * 32 + quad * 8];
#pragma unroll
      for (int kf = 0; kf < 4; kf++)
        af1[kf] = *(const f16x8*)&h1b[(t & 1) * 2176 + l16 * 136 + kf * 32 + quad * 8];
#pragma unroll
      for (int j2 = 0; j2 < 2; j2++) {
        f32x4 zz = {0.f, 0.f, 0.f, 0.f};
#pragma unroll
        for (int kf = 0; kf < 8; kf++)
          zz = MFMA16(af0[kf], wv8[((w * 2 + j2) * 8 + kf) * 64 + lane], zz);
#pragma unroll
        for (int kf = 0; kf < 4; kf++)
          zz = MFMA16(af1[kf], wv8[4096 + ((w * 2 + j2) * 4 + kf) * 64 + lane], zz);
#pragma unroll
        for (int r = 0; r < 4; r++)
          zL[(quad * 4 + r) * 132 + w * 32 + j2 * 16 + l16] = zz[r];
      }
      LBAR();
      {
        int sq = tid >> 5, un = tid & 31;
        f16* dst = h1b + ((t + 1) & 1) * 2176;
        ushort hh[2];
#pragma unroll
        for (int e = 0; e < 2; e++) {
          int s = sq + 8 * e;
          float gi = sigm(zL[s * 132 + un] + bth[0]);
          float ff = sigm(zL[s * 132 + 32 + un] + bth[1]);
          float gg = reluf(zL[s * 132 + 64 + un] + bth[2]);
          float oo = sigm(zL[s * 132 + 96 + un] + bth[3]);
          c1[e] = ff * c1[e] + gi * gg;
          float hv = oo * reluf(c1[e]);
          hh[e] = f2h(hv);
          dst[s * 136 + 32 * bn + un] = __builtin_bit_cast(f16, hh[e]);
        }
        // coalesced publish: rec = bn*256 + tid (tid = sq*32+un)
        u64 tg = ((u64)(uint)(t + 1)) << 32;
        str64(h1rg + (size_t)(t & 7) * 1024 + bn * 256 + tid,
              tg | (u64)((uint)hh[0] | ((uint)hh[1] << 16)));
      }
      LBAR();
    }
  } else if (role == 8) {
    // ================= paragraph L2 + dense tail ============================
    f16* wlds = (f16*)smem;                  // W2 @0 (4096 f16x8), U2 @4096
    f16* h1c  = (f16*)(smem + 98304);        // [2][16*136]
    f16* h2db = (f16*)(smem + 107008);       // [2][16*72]
    {
      const uint4* W2q = (const uint4*)A.W2f;
      const uint4* U2q = (const uint4*)A.U2f;
      uint4* wq = (uint4*)wlds;
      for (int idx = tid; idx < 4096; idx += 256) wq[idx] = W2q[idx];
      for (int idx = tid; idx < 2048; idx += 256) wq[4096 + idx] = U2q[idx];
    }
    for (int idx = tid; idx < 1152; idx += 256) h2db[idx] = (f16)0.f;
    float c2[4] = {0.f, 0.f, 0.f, 0.f};
    float b2[4];
#pragma unroll
    for (int gm = 0; gm < 4; gm++) b2[gm] = A.pl2_b[gm * 64 + 16 * w + l16];
    u64* h1rg = A.h1r + (size_t)g * 8192;
    const f16x8* wv8 = (const f16x8*)wlds;
    __syncthreads();

    for (int t = 0; t < 512; t++) {
      const u64* ra[4]; uint nd[4]; u64 rv[4];
      {
        const u64* s1b = h1rg + (size_t)(t & 7) * 1024;
#pragma unroll
        for (int e = 0; e < 4; e++) { ra[e] = s1b + tid + 256 * e; nd[e] = (uint)(t + 1); }
      }
      poll_recs<4>(ra, nd, rv);
      {
        f16* dst = h1c + (t & 1) * 2176;
#pragma unroll
        for (int e = 0; e < 4; e++) {
          int idx = tid + 256 * e;
          int bq = idx >> 8, r = idx & 255;
          int sqc = r >> 5, unc = r & 31;      // rec = sq*32+un
          uint pay = (uint)rv[e];
          dst[sqc * 136 + bq * 32 + unc]       = __builtin_bit_cast(f16, (ushort)pay);
          dst[(sqc + 8) * 136 + bq * 32 + unc] = __builtin_bit_cast(f16, (ushort)(pay >> 16));
        }
      }
      LBAR();
      if (tid == 0) STRLX(mytag, (uint)(t + 1));    // consumption signal (bp)
      f16x8 af0[4], af1[2];
#pragma unroll
      for (int kf = 0; kf < 4; kf++)
        af0[kf] = *(const f16x8*)&h1c[(t & 1) * 2176 + l16 * 136 + kf * 32 + quad * 8];
#pragma unroll
      for (int kf = 0; kf < 2; kf++)
        af1[kf] = *(const f16x8*)&h2db[(t & 1) * 1152 + l16 * 72 + kf * 32 + quad * 8];
      f32x4 z[4];
#pragma unroll
      for (int gm = 0; gm < 4; gm++) {
        f32x4 zz = {0.f, 0.f, 0.f, 0.f};
#pragma unroll
        for (int kf = 0; kf < 4; kf++)
          zz = MFMA16(af0[kf], wv8[((gm * 4 + w) * 4 + kf) * 64 + lane], zz);
#pragma unroll
        for (int kf = 0; kf < 2; kf++)
          zz = MFMA16(af1[kf], wv8[4096 + ((gm * 4 + w) * 2 + kf) * 64 + lane], zz);
        z[gm] = zz;
      }
#pragma unroll
      for (int r = 0; r < 4; r++) {
        float gi = sigm(z[0][r] + b2[0]);
        float ff = sigm(z[1][r] + b2[1]);
        float gg = reluf(z[2][r] + b2[2]);
        float oo = sigm(z[3][r] + b2[3]);
        c2[r] = ff * c2[r] + gi * gg;
        h2db[((t + 1) & 1) * 1152 + (quad * 4 + r) * 72 + 16 * w + l16] = (f16)(oo * reluf(c2[r]));
      }
    }
    __syncthreads();
    // dense tail -> feat cols 32..63
    float* zmA = (float*)smem;                // 16*132
    float* zmB = (float*)(smem + 8448);       // 16*68
    const f16* hf = h2db;                     // parity 0
#pragma unroll 1
    for (int e = 0; e < 8; e++) {
      const int idx = tid + 256 * e, sq = idx >> 7, j = idx & 127;
      float a = A.pd0b[j];
      for (int k = 0; k < 64; k++) a += (float)hf[sq * 72 + k] * A.pd0W[k * 128 + j];
      zmA[sq * 132 + j] = reluf(a);
    }
    __syncthreads();
#pragma unroll 1
    for (int e = 0; e < 4; e++) {
      const int idx = tid + 256 * e, sq = idx >> 6, j = idx & 63;
      float a = A.pd1b[j];
      for (int k = 0; k < 128; k++) a += zmA[sq * 132 + k] * A.pd1W[k * 64 + j];
      zmB[sq * 68 + j] = reluf(a);
    }
    __syncthreads();
#pragma unroll 1
    for (int e = 0; e < 2; e++) {
      const int idx = tid + 256 * e, sq = idx >> 5, j = idx & 31;
      float a = A.pd2b[j];
      for (int k = 0; k < 64; k++) a += zmB[sq * 68 + k] * A.pd2W[k * 32 + j];
      A.feat[(g * 16 + sq) * 64 + 32 + j] = a;
    }
  } else if (role < 11) {
    // ================= title L0: units 64*bb.., 64KB LDS ====================
    const int bb = role - 9;
    f16* wlds = (f16*)smem;                  // [gm4][wv4][kf4][64]
    f16* hb   = (f16*)(smem + 65536);        // [2][16*136]
    {
      const uint4* U0tq = (const uint4*)A.U0tf;
      uint4* wq = (uint4*)wlds;
      for (int idx = tid; idx < 4096; idx += 256) {
        int gm = idx >> 10, r = idx & 1023, wv = r >> 8, kf = (r >> 6) & 3, ln = r & 63;
        wq[idx] = U0tq[((gm * 8 + 4 * bb + wv) * 4 + kf) * 64 + ln];
      }
    }
    for (int idx = tid; idx < 2176; idx += 256) hb[idx] = (f16)0.f;
    float c0[4] = {0.f, 0.f, 0.f, 0.f};
    u64* ringg = A.h0tr + (size_t)g * 8192;
    const u64* xtq = (const u64*)A.xt2;
    const f16x8* wv8 = (const f16x8*)wlds;
    const int myu = 64 * bb + 16 * w + l16;
    const int pbb = bb ^ 1;
    uint* bpp = A.cnt + (11 * 8 + g) * 16;
    uint* tflg = A.tfl + g * 16;
    __syncthreads();

    for (int t = 0; t < 64; t++) {
      {
        uint* pp = bpp; uint need = 0; bool act = false;
        if (lane == 0) { act = (t > 0) && ((t & 3) == 0); need = t > 4 ? (uint)(t - 4) : 0u; }
        else if (lane == 1) { act = ((t & 3) == 0); need = 1u; pp = tflg + (t >> 2); }
        poll_all(pp, need, act);
      }
      u64 xs[4];
      {
        size_t xb = ((size_t)(g * 64 + t) * 4) * 512 + (size_t)myu * 4 + quad;
#pragma unroll
        for (int gm = 0; gm < 4; gm++) xs[gm] = ldr64(xtq + xb + (size_t)gm * 512);
      }
      {
        const u64* ra[2]; uint nd[2]; u64 rv[2];
        const u64* rb = ringg + (size_t)((t + 7) & 7) * 1024 + pbb * 512 + 2 * tid;
        ra[0] = rb; ra[1] = rb + 1;
        nd[0] = nd[1] = (t > 0) ? (uint)t : 0u;
        poll_recs<2>(ra, nd, rv);
        if (t > 0) {
          f16* dst = hb + (t & 1) * 2176;
          const int ul = tid >> 2;
#pragma unroll
          for (int j = 0; j < 2; j++) {
            uint pay = (uint)rv[j];
            int r0 = ((tid & 3) * 2 + j) * 2;
            dst[r0 * 136 + pbb * 64 + ul]       = __builtin_bit_cast(f16, (ushort)pay);
            dst[(r0 + 1) * 136 + pbb * 64 + ul] = __builtin_bit_cast(f16, (ushort)(pay >> 16));
          }
        }
      }
      LBAR();
      f16x8 af[4];
#pragma unroll
      for (int kf = 0; kf < 4; kf++)
        af[kf] = *(const f16x8*)&hb[(t & 1) * 2176 + l16 * 136 + kf * 32 + quad * 8];
      f32x4 z[4];
#pragma unroll
      for (int gm = 0; gm < 4; gm++) {
        f32x4 zz = {0.f, 0.f, 0.f, 0.f};
#pragma unroll
        for (int kf = 0; kf < 4; kf++)
          zz = MFMA16(af[kf], wv8[((gm * 4 + w) * 4 + kf) * 64 + lane], zz);
        z[gm] = zz;
      }
      ushort hs[4];
      f16* wbuf = hb + ((t + 1) & 1) * 2176;
#pragma unroll
      for (int r = 0; r < 4; r++) {
        float gi = sigm(z[0][r] + h2f((ushort)(xs[0] >> (16 * r))));
        float ff = sigm(z[1][r] + h2f((ushort)(xs[1] >> (16 * r))));
        float gg = reluf(z[2][r] + h2f((ushort)(xs[2] >> (16 * r))));
        float oo = sigm(z[3][r] + h2f((ushort)(xs[3] >> (16 * r))));
        c0[r] = ff * c0[r] + gi * gg;
        hs[r] = f2h(oo * reluf(c0[r]));
        wbuf[(quad * 4 + r) * 136 + myu] = __builtin_bit_cast(f16, hs[r]);
      }
      {
        u64 tg = ((u64)(uint)(t + 1)) << 32;
        u64* wb = ringg + (size_t)(t & 7) * 1024 + bb * 512 + (16 * w + l16) * 8 + quad * 2;
        str64(wb,     tg | (u64)((uint)hs[0] | ((uint)hs[1] << 16)));
        str64(wb + 1, tg | (u64)((uint)hs[2] | ((uint)hs[3] << 16)));
      }
    }
  } else {
    // ================= title L1 + dense tail ================================
    f16* wlds = (f16*)smem;                  // W1t @0, U1t @4096 (f16x8 units)
    f16* h0tc = (f16*)(smem + 98304);        // [2][16*136]
    f16* h1db = (f16*)(smem + 107008);       // [2][16*72]
    {
      const uint4* W1tq = (const uint4*)A.W1tf;
      const uint4* U1tq = (const uint4*)A.U1tf;
      uint4* wq = (uint4*)wlds;
      for (int idx = tid; idx < 4096; idx += 256) wq[idx] = W1tq[idx];
      for (int idx = tid; idx < 2048; idx += 256) wq[4096 + idx] = U1tq[idx];
    }
    for (int idx = tid; idx < 1152; idx += 256) h1db[idx] = (f16)0.f;
    float c1[4] = {0.f, 0.f, 0.f, 0.f};
    float bt[4];
#pragma unroll
    for (int gm = 0; gm < 4; gm++) bt[gm] = A.tl1_b[gm * 64 + 16 * w + l16];
    u64* ringg = A.h0tr + (size_t)g * 8192;
    const f16x8* wv8 = (const f16x8*)wlds;
    __syncthreads();

    for (int t = 0; t < 64; t++) {
      const u64* ra[4]; uint nd[4]; u64 rv[4];
      {
        const u64* base = ringg + (size_t)(t & 7) * 1024;
#pragma unroll
        for (int e = 0; e < 4; e++) { ra[e] = base + tid + 256 * e; nd[e] = (uint)(t + 1); }
      }
      poll_recs<4>(ra, nd, rv);
      {
        f16* dst = h0tc + (t & 1) * 2176;
#pragma unroll
        for (int e = 0; e < 4; e++) {
          int idx = tid + 256 * e;
          int q = idx >> 9, rr = idx & 511, uls = rr >> 3, rp = rr & 7;
          uint pay = (uint)rv[e];
          dst[(2 * rp) * 136 + q * 64 + uls]     = __builtin_bit_cast(f16, (ushort)pay);
          dst[(2 * rp + 1) * 136 + q * 64 + uls] = __builtin_bit_cast(f16, (ushort)(pay >> 16));
        }
      }
      LBAR();
      if (tid == 0) STRLX(mytag, (uint)(t + 1));    // consumption signal (bp)
      f16x8 af0[4], af1[2];
#pragma unroll
      for (int kf = 0; kf < 4; kf++)
        af0[kf] = *(const f16x8*)&h0tc[(t & 1) * 2176 + l16 * 136 + kf * 32 + quad * 8];
#pragma unroll
      for (int kf = 0; kf < 2; kf++)
        af1[kf] = *(const f16x8*)&h1db[(t & 1) * 1152 + l16 * 72 + kf * 32 + quad * 8];
      f32x4 z[4];
#pragma unroll
      for (int gm = 0; gm < 4; gm++) {
        f32x4 zz = {0.f, 0.f, 0.f, 0.f};
#pragma unroll
        for (int kf = 0; kf < 4; kf++)
          zz = MFMA16(af0[kf], wv8[((gm * 4 + w) * 4 + kf) * 64 + lane], zz);
#pragma unroll
        for (int kf = 0; kf < 2; kf++)
          zz = MFMA16(af1[kf], wv8[4096 + ((gm * 4 + w) * 2 + kf) * 64 + lane], zz);
        z[gm] = zz;
      }
#pragma unroll
      for (int r = 0; r < 4; r++) {
        float gi = sigm(z[0][r] + bt[0]);
        float ff = sigm(z[1][r] + bt[1]);
        float gg = reluf(z[2][r] + bt[2]);
        float oo = sigm(z[3][r] + bt[3]);
        c1[r] = ff * c1[r] + gi * gg;
        h1db[((t + 1) & 1) * 1152 + (quad * 4 + r) * 72 + 16 * w + l16] = (f16)(oo * reluf(c1[r]));
      }
    }
    __syncthreads();
    // dense tail -> feat cols 0..31
    float* zmA = (float*)smem;
    float* zmB = (float*)(smem + 8448);
    const f16* hf = h1db;                    // parity 0
#pragma unroll 1
    for (int e = 0; e < 8; e++) {
      const int idx = tid + 256 * e, sq = idx >> 7, j = idx & 127;
      float a = A.td0b[j];
      for (int k = 0; k < 64; k++) a += (float)hf[sq * 72 + k] * A.td0W[k * 128 + j];
      zmA[sq * 132 + j] = reluf(a);
    }
    __syncthreads();
#pragma unroll 1
    for (int e = 0; e < 4; e++) {
      const int idx = tid + 256 * e, sq = idx >> 6, j = idx & 63;
      float a = A.td1b[j];
      for (int k = 0; k < 128; k++) a += zmA[sq * 132 + k] * A.td1W[k * 64 + j];
      zmB[sq * 68 + j] = reluf(a);
    }
    __syncthreads();
#pragma unroll 1
    for (int e = 0; e < 2; e++) {
      const int idx = tid + 256 * e, sq = idx >> 5, j = idx & 31;
      float a = A.td2b[j];
      for (int k = 0; k < 64; k++) a += zmB[sq * 68 + k] * A.td2W[k * 32 + j];
      A.feat[(g * 16 + sq) * 64 + j] = a;
    }
  }
}

// ---------------- head
__global__ __launch_bounds__(256) void head_kernel(const float* __restrict__ feat,
    const float* __restrict__ L0W, const float* __restrict__ L0b,
    const float* __restrict__ L1W, const float* __restrict__ L1b,
    const float* __restrict__ L2W, const float* __restrict__ L2b,
    const float* __restrict__ L3W, const float* __restrict__ L3b,
    float* __restrict__ out) {
  __shared__ float xb[512];
  __shared__ float y0[2048];
  __shared__ float y1[1024];
  __shared__ float y2[512];
  const int tid = threadIdx.x;
  for (int idx = tid; idx < 512; idx += 256) {
    int b = idx >> 6, d = idx & 63;
    float s = 0.f;
    for (int n = 0; n < 16; n++) s += feat[(b * 16 + n) * 64 + d];
    xb[idx] = s * (1.f / 16.f);
  }
  __syncthreads();
  for (int idx = tid; idx < 2048; idx += 256) {
    int b = idx >> 8, j = idx & 255;
    float a = L0b[j];
    for (int k = 0; k < 64; k++) a += xb[b * 64 + k] * L0W[k * 256 + j];
    y0[idx] = reluf(a);
  }
  __syncthreads();
  for (int idx = tid; idx < 1024; idx += 256) {
    int b = idx >> 7, j = idx & 127;
    float a = L1b[j];
    for (int k = 0; k < 256; k++) a += y0[b * 256 + k] * L1W[k * 128 + j];
    y1[idx] = reluf(a);
  }
  __syncthreads();
  for (int idx = tid; idx < 512; idx += 256) {
    int b = idx >> 6, j = idx & 63;
    float a = L2b[j];
    for (int k = 0; k < 128; k++) a += y1[b * 128 + k] * L2W[k * 64 + j];
    y2[idx] = reluf(a);
  }
  __syncthreads();
  {
    int b = tid >> 5, j = tid & 31;
    float a = L3b[j];
    for (int k = 0; k < 64; k++) a += y2[b * 64 + k] * L3W[k * 32 + j];
    out[b * 32 + j] = 1.f / (1.f + __expf(-a));
  }
}

extern "C" void kernel_launch(void* const* d_in, const int* in_sizes, int n_in,
                              void* d_out, int out_size, void* d_ws, size_t ws_size,
                              hipStream_t stream) {
  const int*   t_tok = (const int*)d_in[0];
  const int*   p_tok = (const int*)d_in[1];
  const float* emb_t = (const float*)d_in[2];
  const float* emb_p = (const float*)d_in[3];
  const float* tl0_W = (const float*)d_in[4];
  const float* tl0_U = (const float*)d_in[5];
  const float* tl0_b = (const float*)d_in[6];
  const float* tl1_W = (const float*)d_in[7];
  const float* tl1_U = (const float*)d_in[8];
  const float* tl1_b = (const float*)d_in[9];
  const float* td0_W = (const float*)d_in[10];
  const float* td0_b = (const float*)d_in[11];
  const float* td1_W = (const float*)d_in[12];
  const float* td1_b = (const float*)d_in[13];
  const float* td2_W = (const float*)d_in[14];
  const float* td2_b = (const float*)d_in[15];
  const float* pl0_W = (const float*)d_in[16];
  const float* pl0_U = (const float*)d_in[17];
  const float* pl0_b = (const float*)d_in[18];
  const float* pl1_W = (const float*)d_in[19];
  const float* pl1_U = (const float*)d_in[20];
  const float* pl1_b = (const float*)d_in[21];
  const float* pl2_W = (const float*)d_in[22];
  const float* pl2_U = (const float*)d_in[23];
  const float* pl2_b = (const float*)d_in[24];
  const float* pd0_W = (const float*)d_in[25];
  const float* pd0_b = (const float*)d_in[26];
  const float* pd1_W = (const float*)d_in[27];
  const float* pd1_b = (const float*)d_in[28];
  const float* pd2_W = (const float*)d_in[29];
  const float* pd2_b = (const float*)d_in[30];
  const float* L0_W  = (const float*)d_in[31];
  const float* L0_b  = (const float*)d_in[32];
  const float* L1_W  = (const float*)d_in[33];
  const float* L1_b  = (const float*)d_in[34];
  const float* L2_W  = (const float*)d_in[35];
  const float* L2_b  = (const float*)d_in[36];
  const float* L3_W  = (const float*)d_in[37];
  const float* L3_b  = (const float*)d_in[38];

  char* ws = (char*)d_ws;
  size_t off = 0;
  auto alloc = [&](size_t bytes) {
    void* ptr = ws + off;
    off += (bytes + 255) & ~(size_t)255;
    return ptr;
  };
  f16* xp2  = (f16*)alloc((size_t)8 * 512 * 4 * 4096 * 2);     // 128 MB
  f16* xt2  = (f16*)alloc((size_t)8 * 64 * 4 * 2048 * 2);      // 8 MB
  f16* Bp   = (f16*)alloc((size_t)256 * 1024 * 2);
  f16* Bt   = (f16*)alloc((size_t)128 * 512 * 2);
  f16* U0f  = (f16*)alloc((size_t)256 * 1024 * 2);
  f16* W1f  = (f16*)alloc((size_t)256 * 512 * 2);
  f16* U1f  = (f16*)alloc((size_t)128 * 512 * 2);
  f16* W2f  = (f16*)alloc((size_t)128 * 256 * 2);
  f16* U2f  = (f16*)alloc((size_t)64 * 256 * 2);
  f16* U0tf = (f16*)alloc((size_t)128 * 512 * 2);
  f16* W1tf = (f16*)alloc((size_t)128 * 256 * 2);
  f16* U1tf = (f16*)alloc((size_t)64 * 256 * 2);
  size_t ringoff = off;
  u64* h0r  = (u64*)alloc((size_t)8 * 16384 * 8);              // 1 MB
  u64* h1r  = (u64*)alloc((size_t)8 * 8192 * 8);               // 512 KB
  u64* h0tr = (u64*)alloc((size_t)8 * 8192 * 8);               // 512 KB
  uint* cnt = (uint*)alloc((size_t)96 * 16 * 4);
  uint* xfl = (uint*)alloc((size_t)8 * 128 * 4);
  uint* tfl = (uint*)alloc((size_t)8 * 16 * 4);
  size_t ringlen = off - ringoff;
  float* feat = (float*)alloc((size_t)128 * 64 * 4);

  // rings + cnt + X-ready flags MUST be zeroed every replay (stale tags or
  // flags from a prior replay would false-validate).
  hipMemsetAsync(ws + ringoff, 0, ringlen, stream);

  pack_bsw<4><<<256, 256, 0, stream>>>(tl0_W, Bt, 512);
  pack_bsw<8><<<1024, 256, 0, stream>>>(pl0_W, Bp, 1024);
  pack_bsw<8><<<1024, 256, 0, stream>>>(pl0_U, U0f, 1024);
  pack_bsw<8><<<512, 256, 0, stream>>>(pl1_W, W1f, 512);
  pack_bsw<4><<<256, 256, 0, stream>>>(pl1_U, U1f, 512);
  pack_bsw<4><<<128, 256, 0, stream>>>(pl2_W, W2f, 256);
  pack_bsw<2><<<64, 256, 0, stream>>>(pl2_U, U2f, 256);
  pack_bsw<4><<<256, 256, 0, stream>>>(tl0_U, U0tf, 512);
  pack_bsw<4><<<128, 256, 0, stream>>>(tl1_W, W1tf, 256);
  pack_bsw<2><<<64, 256, 0, stream>>>(tl1_U, U1tf, 256);

  RP ra;
  ra.t_tok = t_tok; ra.p_tok = p_tok; ra.emb_t = emb_t; ra.emb_p = emb_p;
  ra.Bp = Bp; ra.Bt = Bt; ra.tl0_b = tl0_b; ra.pl0_b = pl0_b;
  ra.xp2 = xp2; ra.xt2 = xt2;
  ra.U0f = U0f; ra.W1f = W1f; ra.U1f = U1f; ra.W2f = W2f; ra.U2f = U2f;
  ra.U0tf = U0tf; ra.W1tf = W1tf; ra.U1tf = U1tf;
  ra.pl1_b = pl1_b; ra.pl2_b = pl2_b; ra.tl1_b = tl1_b;
  ra.pd0W = pd0_W; ra.pd0b = pd0_b; ra.pd1W = pd1_W; ra.pd1b = pd1_b;
  ra.pd2W = pd2_W; ra.pd2b = pd2_b;
  ra.td0W = td0_W; ra.td0b = td0_b; ra.td1W = td1_W; ra.td1b = td1_b;
  ra.td2W = td2_W; ra.td2b = td2_b;
  ra.h0r = h0r; ra.h1r = h1r; ra.h0tr = h0tr;
  ra.cnt = cnt; ra.xfl = xfl; ra.tfl = tfl;
  ra.feat = feat;
  fused<<<256, 256, 0, stream>>>(ra);

  head_kernel<<<1, 256, 0, stream>>>(feat, L0_W, L0_b, L1_W, L1_b, L2_W, L2_b,
                                     L3_W, L3_b, (float*)d_out);
}

// Round 9
// 1387.185 us; speedup vs baseline: 1.4173x; 1.0154x over previous
//
#include <hip/hip_runtime.h>
#include <hip/hip_fp16.h>

typedef _Float16 f16;
typedef _Float16 f16x8 __attribute__((ext_vector_type(8)));
typedef float    f32x4 __attribute__((ext_vector_type(4)));
typedef unsigned short ushort;
typedef unsigned int uint;
typedef unsigned long long u64;

__device__ __forceinline__ float sigm(float x) { return 1.f / (1.f + __expf(-x)); }
__device__ __forceinline__ float reluf(float x) { return x > 0.f ? x : 0.f; }
__device__ __forceinline__ float h2f(ushort u) { return (float)__builtin_bit_cast(f16, u); }
__device__ __forceinline__ ushort f2h(float v) { return __builtin_bit_cast(ushort, (f16)v); }

#define LDRLX(p)    __hip_atomic_load((p), __ATOMIC_RELAXED, __HIP_MEMORY_SCOPE_AGENT)
#define STRLX(p, v) __hip_atomic_store((p), (v), __ATOMIC_RELAXED, __HIP_MEMORY_SCOPE_AGENT)
#define MFMA16(a, b, c) __builtin_amdgcn_mfma_f32_16x16x32_f16((a), (b), (c), 0, 0, 0)
// lgkm-only barrier: orders LDS without draining vmcnt (ring publishes stay in
// flight across step barriers; correctness = tag-in-data + backpressure).
#define LBAR() do { asm volatile("s_waitcnt lgkmcnt(0)" ::: "memory"); \
                    __builtin_amdgcn_s_barrier(); } while (0)

__device__ __forceinline__ float ldf(const float* p) {
  return __hip_atomic_load(p, __ATOMIC_RELAXED, __HIP_MEMORY_SCOPE_AGENT);
}
__device__ __forceinline__ void stf(float* p, float v) {
  __hip_atomic_store(p, v, __ATOMIC_RELAXED, __HIP_MEMORY_SCOPE_AGENT);
}

// Backpressure / flag poll (agent scope; amortized off critical path).
__device__ __forceinline__ void poll_all(uint* p, uint need, bool act) {
  bool done = !act;
  while (true) {
    if (!done) done = (LDRLX(p) >= need);
    if (__all((int)done)) break;
    __builtin_amdgcn_s_sleep(1);
  }
}

__device__ __forceinline__ u64 ldr64(const u64* p) {
  return __hip_atomic_load(p, __ATOMIC_RELAXED, __HIP_MEMORY_SCOPE_AGENT);
}
__device__ __forceinline__ void str64(u64* p, u64 v) {
  __hip_atomic_store(p, v, __ATOMIC_RELAXED, __HIP_MEMORY_SCOPE_AGENT);
}

// Tag-in-data record poll: each u64 record = {tag:32 | payload(2xf16):32}.
template <int NR>
__device__ __forceinline__ void poll_recs(const u64* const (&ra)[NR],
                                          const uint (&nd)[NR], u64 (&rv)[NR]) {
  bool ok[NR];
#pragma unroll
  for (int i = 0; i < NR; i++) ok[i] = (nd[i] == 0u);
  while (true) {
    bool all = true;
#pragma unroll
    for (int i = 0; i < NR; i++) if (!ok[i]) rv[i] = ldr64(ra[i]);
#pragma unroll
    for (int i = 0; i < NR; i++) if (!ok[i]) ok[i] = ((uint)(rv[i] >> 32) >= nd[i]);
#pragma unroll
    for (int i = 0; i < NR; i++) all &= ok[i];
    if (all) return;
    __builtin_amdgcn_s_sleep(1);
  }
}

// ---------------- prep: 10 pack regions (validated pack_bsw formula) + ring
// zeroing, consolidated into ONE launch (was 10 pack launches + memset).
struct PrepA {
  const float* src[10];
  f16* dst[10];
  int kfm[10];   // KF-1 (mask)
  int lg[10];    // log2(KF)
  int nn[10];    // N
  int total[10];
  int bo[10];    // starting block of region
  int packBlocks;
  u64* zb;       // zero base
  long zn;       // zero count (u64s)
};

__global__ __launch_bounds__(256) void prep(PrepA P) {
  const int blk = blockIdx.x;
  if (blk < P.packBlocks) {
    int r = 0;
#pragma unroll
    for (int i = 1; i < 10; i++) if (blk >= P.bo[i]) r = i;
    int id = (blk - P.bo[r]) * 256 + threadIdx.x;
    if (id < P.total[r]) {
      int j  = id & 7;
      int L  = (id >> 3) & 63;
      int rr = id >> 9;
      int kf = rr & P.kfm[r];
      int c  = rr >> P.lg[r];
      int k  = kf * 32 + ((L >> 4) * 8) + j;
      int n  = c * 16 + (L & 15);
      P.dst[r][id] = (f16)P.src[r][k * P.nn[r] + n];
    }
  } else {
    long i = (long)(blk - P.packBlocks) * 256 + threadIdx.x;
    if (i < P.zn) P.zb[i] = 0;
  }
}

struct RP {
  const int *t_tok, *p_tok;
  const float *emb_t, *emb_p;
  const f16 *Bp, *Bt;
  const float *tl0_b, *pl0_b;
  f16 *xp2, *xt2;
  const f16 *U0f, *W1f, *U1f, *W2f, *U2f, *U0tf, *W1tf, *U1tf;
  const float *pl1_b, *pl2_b, *tl1_b;
  const float *pd0W, *pd0b, *pd1W, *pd1b, *pd2W, *pd2b;
  const float *td0W, *td0b, *td1W, *td1b, *td2W, *td2b;
  const float *L0W, *L0b, *L1W, *L1b, *L2W, *L2b, *L3W, *L3b;
  u64 *h0r, *h1r, *h0tr;
  uint *cnt, *xfl, *tfl, *ffl;
  float* feat;
  float* out;
};

// ---------------- worker xW GEMM tile (R6 gemm_xw body; X stores are
// AGENT-SCOPE u64 so consumers on other XCDs see them without kernel-boundary
// flushes; trailing __syncthreads drains vmcnt before the caller's flag store).
template <int Sx, int K, int KF, int N, int NC, int MODE>
__device__ __forceinline__ void gemm_tile(int g, int t0,
    const int* __restrict__ tok, const float* __restrict__ emb,
    const f16* __restrict__ Bsw, const float* __restrict__ bias,
    u64* __restrict__ X, char* smem) {
  int* tokLds = (int*)smem;                  // 256B
  f16x8* bLds = (f16x8*)(smem + 1024);       // 8KB max
  const int tid = threadIdx.x;
  if (tid < 64) {
    int wv = tid >> 4, rho = tid & 15;
    tokLds[tid] = tok[(g * 16 + rho) * Sx + t0 + wv];
  }
  __syncthreads();
  const int wave = tid >> 6, lane = tid & 63;
  const int quad = lane >> 4, l16 = lane & 15;
  f16x8 a[KF];
  {
    const float* arow = emb + (long)tokLds[wave * 16 + l16] * K + quad * 8;
#pragma unroll
    for (int kf = 0; kf < KF; kf++) {
      float4 v0 = *(const float4*)(arow + kf * 32);
      float4 v1 = *(const float4*)(arow + kf * 32 + 4);
      f16x8 tv;
      tv[0] = (f16)v0.x; tv[1] = (f16)v0.y; tv[2] = (f16)v0.z; tv[3] = (f16)v0.w;
      tv[4] = (f16)v1.x; tv[5] = (f16)v1.y; tv[6] = (f16)v1.z; tv[7] = (f16)v1.w;
      a[kf] = tv;
    }
  }
  const int t = t0 + wave;
  const f16x8* Bfrag = (const f16x8*)Bsw;
  for (int c = 0; c < NC; c++) {
    __syncthreads();                         // prev iter's bLds readers done
    for (int i = tid; i < KF * 64; i += 256) bLds[i] = Bfrag[c * KF * 64 + i];
    __syncthreads();
    f32x4 acc = {0.f, 0.f, 0.f, 0.f};
#pragma unroll
    for (int kf = 0; kf < KF; kf++)
      acc = MFMA16(a[kf], bLds[kf * 64 + lane], acc);
    const int col = c * 16 + l16;
    const float bc = bias[col];
    uint lo = (uint)f2h(acc[0] + bc) | ((uint)f2h(acc[1] + bc) << 16);
    uint hi = (uint)f2h(acc[2] + bc) | ((uint)f2h(acc[3] + bc) << 16);
    u64 pv = (u64)lo | ((u64)hi << 32);
    size_t b64;
    if (MODE == 0) {
      int gm = col >> 8, u = col & 255;
      b64 = (((size_t)(g * 512 + t) * 4 + gm) * 1024) + u * 4 + quad;
    } else {
      int gm = col >> 7, u = col & 127;
      b64 = (((size_t)(g * 64 + t) * 4 + gm) * 512) + u * 4 + quad;
    }
    str64(X + b64, pv);
  }
  __syncthreads();                           // drain all waves' X stores
}

// ---------------- head (device body; runs in worker 159 after feat flags)
__device__ void head_body(const RP& A, char* smem) {
  const int tid = threadIdx.x;
  const int lane = tid & 63;
  poll_all(A.ffl + (lane & 15), 1u, lane < 16);   // all 16 feat tiles published
  __syncthreads();
  float* xb = (float*)smem;                // 512 f
  float* y0 = (float*)(smem + 2048);       // 2048 f
  float* y1 = (float*)(smem + 10240);      // 1024 f
  float* y2 = (float*)(smem + 14336);      // 512 f
  for (int idx = tid; idx < 512; idx += 256) {
    int b = idx >> 6, d = idx & 63;
    float s = 0.f;
    for (int n = 0; n < 16; n++) s += ldf(A.feat + (b * 16 + n) * 64 + d);
    xb[idx] = s * (1.f / 16.f);
  }
  __syncthreads();
  for (int idx = tid; idx < 2048; idx += 256) {
    int b = idx >> 8, j = idx & 255;
    float a = A.L0b[j];
    for (int k = 0; k < 64; k++) a += xb[b * 64 + k] * A.L0W[k * 256 + j];
    y0[idx] = reluf(a);
  }
  __syncthreads();
  for (int idx = tid; idx < 1024; idx += 256) {
    int b = idx >> 7, j = idx & 127;
    float a = A.L1b[j];
    for (int k = 0; k < 256; k++) a += y0[b * 256 + k] * A.L1W[k * 128 + j];
    y1[idx] = reluf(a);
  }
  __syncthreads();
  for (int idx = tid; idx < 512; idx += 256) {
    int b = idx >> 6, j = idx & 63;
    float a = A.L2b[j];
    for (int k = 0; k < 128; k++) a += y1[b * 128 + k] * A.L2W[k * 64 + j];
    y2[idx] = reluf(a);
  }
  __syncthreads();
  {
    int b = tid >> 5, j = tid & 31;
    float a = A.L3b[j];
    for (int k = 0; k < 64; k++) a += y2[b * 64 + k] * A.L3W[k * 32 + j];
    A.out[b * 32 + j] = 1.f / (1.f + __expf(-a));
  }
}

__device__ void worker_body(const RP& A, int wid, char* smem) {
  const int tid = threadIdx.x;
  // 1152 tiles ordered (tchunk, g), title first -> early timesteps first.
  for (int tile = wid; tile < 1152; tile += 160) {
    if (tile < 128) {
      int tch = tile >> 3, g = tile & 7;
      gemm_tile<64, 128, 4, 512, 32, 1>(g, tch * 4, A.t_tok, A.emb_t, A.Bt,
                                        A.tl0_b, (u64*)A.xt2, smem);
      if (tid == 0) STRLX(A.tfl + g * 16 + tch, 1u);
    } else {
      int m0 = tile - 128, tch = m0 >> 3, g = m0 & 7;
      gemm_tile<512, 256, 8, 1024, 64, 0>(g, tch * 4, A.p_tok, A.emb_p, A.Bp,
                                          A.pl0_b, (u64*)A.xp2, smem);
      if (tid == 0) STRLX(A.xfl + g * 128 + tch, 1u);
    }
  }
  if (wid == 159) head_body(A, smem);        // head folded into last worker
}

// ---------------- fused persistent kernel: 256 blocks x 256 thr.
// blk 0-95: R12/R6 recurrence (verified) — role = blk>>3, g = blk&7:
//   roles 0-3 paraL0(bb), 4-7 paraL1(bn), 8 paraL2+tail, 9-10 titleL0(bb),
//   11 titleL1+tail. blk 96-255: 160 xW-GEMM workers (tile queue + flags);
//   worker 159 additionally runs the HEAD after polling 16 feat flags.
// All 256 blocks are co-resident (148KB LDS -> 1 block/CU, grid == CU count),
// so the recur<->worker dependency cannot deadlock; workers terminate
// independently, so partial residency also makes progress.
// Cross-XCD data (X, feat) uses agent-scope stores AND loads; every
// flag/tag publish follows a vmcnt-draining __syncthreads (flag-visible =>
// data-visible). Rings/cnt/flags zeroed every replay (by prep).
__global__ __launch_bounds__(256, 1) void fused(RP A) {
  __shared__ __align__(16) char smem[147968];
  const int blk = blockIdx.x;
  if (blk >= 96) { worker_body(A, blk - 96, smem); return; }
  const int tid = threadIdx.x;
  const int w = tid >> 6, lane = tid & 63;
  const int quad = lane >> 4, l16 = lane & 15;
  const int role = blk >> 3, g = blk & 7;
  uint* mytag = A.cnt + (role * 8 + g) * 16;

  if (role < 4) {
    // ================= paragraph L0: units 64*bb.. , weights 128KB LDS =======
    const int bb = role;
    f16* wlds = (f16*)smem;                 // [gm4][wv4][kf8][64] f16x8
    f16* hb   = (f16*)(smem + 131072);      // [2][16*264]
    {
      const uint4* U0q = (const uint4*)A.U0f;
      uint4* wq = (uint4*)wlds;
      for (int idx = tid; idx < 8192; idx += 256) {
        int gm = idx >> 11, r = idx & 2047, wv = r >> 9, kf = (r >> 6) & 7, ln = r & 63;
        wq[idx] = U0q[((gm * 16 + 4 * bb + wv) * 8 + kf) * 64 + ln];
      }
    }
    for (int idx = tid; idx < 4224; idx += 256) hb[idx] = (f16)0.f;
    float c0[4] = {0.f, 0.f, 0.f, 0.f};
    u64* ringg = A.h0r + (size_t)g * 16384;
    int pp3[3]; { int q = 0; for (int p = 0; p < 4; p++) if (p != bb) pp3[q++] = p; }
    const u64* xq2 = (const u64*)A.xp2;
    const f16x8* wv8 = (const f16x8*)wlds;
    const int myu = 64 * bb + 16 * w + l16;
    const int ulq = 16 * ((tid >> 4) & 3) + (tid & 15);   // coalesced-rec decode
    const int qd  = tid >> 6;
    uint* bpp = A.cnt;
    if (lane < 4) bpp = A.cnt + ((4 + lane) * 8 + g) * 16;
    uint* xflg = A.xfl + g * 128;
    __syncthreads();

    for (int t = 0; t < 512; t++) {
      {
        uint* pp = bpp; uint need = 0; bool act = false;
        if (lane < 4) { act = (t > 0) && ((t & 3) == 0); need = t > 4 ? (uint)(t - 4) : 0u; }
        else if (lane == 4) { act = ((t & 3) == 0); need = 1u; pp = xflg + (t >> 2); }
        poll_all(pp, need, act);
      }
      u64 xs[4];
      {
        size_t xb = ((size_t)(g * 512 + t) * 4) * 1024 + (size_t)myu * 4 + quad;
#pragma unroll
        for (int gm = 0; gm < 4; gm++) xs[gm] = ldr64(xq2 + xb + (size_t)gm * 1024);
      }
      {
        const u64* slotb = ringg + (size_t)((t + 7) & 7) * 2048;
        const u64* ra[6]; uint nd[6]; u64 rv[6];
#pragma unroll
        for (int q = 0; q < 3; q++) {
          const u64* rb = slotb + pp3[q] * 512 + 2 * tid;
          ra[q * 2] = rb; ra[q * 2 + 1] = rb + 1;
          nd[q * 2] = nd[q * 2 + 1] = (t > 0) ? (uint)t : 0u;
        }
        poll_recs<6>(ra, nd, rv);
        if (t > 0) {
          f16* dst = hb + (t & 1) * 4224;
#pragma unroll
          for (int q = 0; q < 3; q++)
#pragma unroll
            for (int j = 0; j < 2; j++) {
              uint pay = (uint)rv[q * 2 + j];
              int r0 = qd * 4 + 2 * j;
              dst[r0 * 264 + pp3[q] * 64 + ulq]       = __builtin_bit_cast(f16, (ushort)pay);
              dst[(r0 + 1) * 264 + pp3[q] * 64 + ulq] = __builtin_bit_cast(f16, (ushort)(pay >> 16));
            }
        }
      }
      LBAR();
      f16x8 af[8];
#pragma unroll
      for (int kf = 0; kf < 8; kf++)
        af[kf] = *(const f16x8*)&hb[(t & 1) * 4224 + l16 * 264 + kf * 32 + quad * 8];
      f32x4 z[4];
#pragma unroll
      for (int gm = 0; gm < 4; gm++) {
        f32x4 zz = {0.f, 0.f, 0.f, 0.f};
#pragma unroll
        for (int kf = 0; kf < 8; kf++)
          zz = MFMA16(af[kf], wv8[((gm * 4 + w) * 8 + kf) * 64 + lane], zz);
        z[gm] = zz;
      }
      ushort hs[4];
      f16* wbuf = hb + ((t + 1) & 1) * 4224;
#pragma unroll
      for (int r = 0; r < 4; r++) {
        float gi = sigm(z[0][r] + h2f((ushort)(xs[0] >> (16 * r))));
        float ff = sigm(z[1][r] + h2f((ushort)(xs[1] >> (16 * r))));
        float gg = reluf(z[2][r] + h2f((ushort)(xs[2] >> (16 * r))));
        float oo = sigm(z[3][r] + h2f((ushort)(xs[3] >> (16 * r))));
        c0[r] = ff * c0[r] + gi * gg;
        hs[r] = f2h(oo * reluf(c0[r]));
        wbuf[(quad * 4 + r) * 264 + myu] = __builtin_bit_cast(f16, hs[r]);
      }
      {
        // coalesced publish: rec = bb*512 + quad*128 + w*32 + l16*2 (+j)
        u64 tg = ((u64)(uint)(t + 1)) << 32;
        u64* wb = ringg + (size_t)(t & 7) * 2048 + bb * 512 +
                  quad * 128 + w * 32 + l16 * 2;
        str64(wb,     tg | (u64)((uint)hs[0] | ((uint)hs[1] << 16)));
        str64(wb + 1, tg | (u64)((uint)hs[2] | ((uint)hs[3] << 16)));
      }
    }
  } else if (role < 8) {
    // ================= paragraph L1: units 32*bn.., 96KB LDS weights ========
    const int bn = role - 4;
    f16* wlds = (f16*)smem;                  // W1 @0 (4096 x f16x8), U1 @4096
    f16* h0c  = (f16*)(smem + 98304);        // 16*264
    f16* h1b  = (f16*)(smem + 106752);       // [2][16*136]
    float* zL = (float*)(smem + 115456);     // 16*132
    {
      const uint4* W1q = (const uint4*)A.W1f;
      const uint4* U1q = (const uint4*)A.U1f;
      uint4* wq = (uint4*)wlds;
      for (int idx = tid; idx < 4096; idx += 256) {
        int gm = idx >> 10, r = idx & 1023, j2 = r >> 9, kf = (r >> 6) & 7, ln = r & 63;
        wq[idx] = W1q[((gm * 8 + bn * 2 + j2) * 8 + kf) * 64 + ln];
      }
      for (int idx = tid; idx < 2048; idx += 256) {
        int gm = idx >> 9, r = idx & 511, j2 = r >> 8, kf = (r >> 6) & 3, ln = r & 63;
        wq[4096 + idx] = U1q[((gm * 8 + bn * 2 + j2) * 4 + kf) * 64 + ln];
      }
    }
    for (int idx = tid; idx < 2176; idx += 256) h1b[idx] = (f16)0.f;
    float c1[2] = {0.f, 0.f};
    float bth[4];
    { int un = tid & 31; for (int gm = 0; gm < 4; gm++) bth[gm] = A.pl1_b[gm * 128 + 32 * bn + un]; }
    u64* h0rg = A.h0r + (size_t)g * 16384;
    u64* h1rg = A.h1r + (size_t)g * 8192;
    int pp3[3]; { int q = 0; for (int p = 0; p < 4; p++) if (p != bn) pp3[q++] = p; }
    const f16x8* wv8 = (const f16x8*)wlds;
    uint* bpp = A.cnt + (8 * 8 + g) * 16;
    __syncthreads();

    for (int t = 0; t < 512; t++) {
      {
        bool act = (lane == 0) && ((t & 3) == 0);
        uint need = t > 4 ? (uint)(t - 4) : 0u;
        poll_all(bpp, need, act);
      }
      const u64* ra[11]; uint nd[11]; u64 rv[11];
      {
        const u64* s0b = h0rg + (size_t)(t & 7) * 2048;
#pragma unroll
        for (int e = 0; e < 8; e++) { ra[e] = s0b + tid + 256 * e; nd[e] = (uint)(t + 1); }
        const u64* s1b = h1rg + (size_t)((t + 7) & 7) * 1024;
#pragma unroll
        for (int q = 0; q < 3; q++) { ra[8 + q] = s1b + pp3[q] * 256 + tid; nd[8 + q] = (t > 0) ? (uint)t : 0u; }
      }
      poll_recs<11>(ra, nd, rv);
      {
        // h0 scatter: decode coalesced rec idx -> (bb, quad, w, l16, j)
#pragma unroll
        for (int e = 0; e < 8; e++) {
          int idx = tid + 256 * e;
          int bbq = idx >> 9, r = idx & 511;
          int jj = r & 1, l16c = (r >> 1) & 15, wc = (r >> 5) & 3, qdc = (r >> 7) & 3;
          int col = bbq * 64 + 16 * wc + l16c;
          int r0 = qdc * 4 + 2 * jj;
          uint pay = (uint)rv[e];
          h0c[r0 * 264 + col]       = __builtin_bit_cast(f16, (ushort)pay);
          h0c[(r0 + 1) * 264 + col] = __builtin_bit_cast(f16, (ushort)(pay >> 16));
        }
        if (t > 0) {
          f16* dst = h1b + (t & 1) * 2176;
          int sqc = tid >> 5, unc = tid & 31;   // rec = sq*32+un = tid
#pragma unroll
          for (int q = 0; q < 3; q++) {
            uint pay = (uint)rv[8 + q];
            dst[sqc * 136 + pp3[q] * 32 + unc]       = __builtin_bit_cast(f16, (ushort)pay);
            dst[(sqc + 8) * 136 + pp3[q] * 32 + unc] = __builtin_bit_cast(f16, (ushort)(pay >> 16));
          }
        }
      }
      LBAR();
      if (tid == 0) STRLX(mytag, (uint)(t + 1));    // consumption signal (bp)
      f16x8 af0[8], af1[4];
#pragma unroll
      for (int kf = 0; kf < 8; kf++)
        af0[kf] = *(const f16x8*)&h0c[l16 * 264 + kf * 32 + quad * 8];
#pragma unroll
      for (int kf = 0; kf < 4; kf++)
        af1[kf] = *(const f16x8*)&h1b[(t & 1) * 2176 + l16 * 136 + kf * 32 + quad * 8];
#pragma unroll
      for (int j2 = 0; j2 < 2; j2++) {
        f32x4 zz = {0.f, 0.f, 0.f, 0.f};
#pragma unroll
        for (int kf = 0; kf < 8; kf++)
          zz = MFMA16(af0[kf], wv8[((w * 2 + j2) * 8 + kf) * 64 + lane], zz);
#pragma unroll
        for (int kf = 0; kf < 4; kf++)
          zz = MFMA16(af1[kf], wv8[4096 + ((w * 2 + j2) * 4 + kf) * 64 + lane], zz);
#pragma unroll
        for (int r = 0; r < 4; r++)
          zL[(quad * 4 + r) * 132 + w * 32 + j2 * 16 + l16] = zz[r];
      }
      LBAR();
      {
        int sq = tid >> 5, un = tid & 31;
        f16* dst = h1b + ((t + 1) & 1) * 2176;
        ushort hh[2];
#pragma unroll
        for (int e = 0; e < 2; e++) {
          int s = sq + 8 * e;
          float gi = sigm(zL[s * 132 + un] + bth[0]);
          float ff = sigm(zL[s * 132 + 32 + un] + bth[1]);
          float gg = reluf(zL[s * 132 + 64 + un] + bth[2]);
          float oo = sigm(zL[s * 132 + 96 + un] + bth[3]);
          c1[e] = ff * c1[e] + gi * gg;
          float hv = oo * reluf(c1[e]);
          hh[e] = f2h(hv);
          dst[s * 136 + 32 * bn + un] = __builtin_bit_cast(f16, hh[e]);
        }
        // coalesced publish: rec = bn*256 + tid (tid = sq*32+un)
        u64 tg = ((u64)(uint)(t + 1)) << 32;
        str64(h1rg + (size_t)(t & 7) * 1024 + bn * 256 + tid,
              tg | (u64)((uint)hh[0] | ((uint)hh[1] << 16)));
      }
      LBAR();
    }
  } else if (role == 8) {
    // ================= paragraph L2 + dense tail ============================
    f16* wlds = (f16*)smem;                  // W2 @0 (4096 f16x8), U2 @4096
    f16* h1c  = (f16*)(smem + 98304);        // [2][16*136]
    f16* h2db = (f16*)(smem + 107008);       // [2][16*72]
    {
      const uint4* W2q = (const uint4*)A.W2f;
      const uint4* U2q = (const uint4*)A.U2f;
      uint4* wq = (uint4*)wlds;
      for (int idx = tid; idx < 4096; idx += 256) wq[idx] = W2q[idx];
      for (int idx = tid; idx < 2048; idx += 256) wq[4096 + idx] = U2q[idx];
    }
    for (int idx = tid; idx < 1152; idx += 256) h2db[idx] = (f16)0.f;
    float c2[4] = {0.f, 0.f, 0.f, 0.f};
    float b2[4];
#pragma unroll
    for (int gm = 0; gm < 4; gm++) b2[gm] = A.pl2_b[gm * 64 + 16 * w + l16];
    u64* h1rg = A.h1r + (size_t)g * 8192;
    const f16x8* wv8 = (const f16x8*)wlds;
    __syncthreads();

    for (int t = 0; t < 512; t++) {
      const u64* ra[4]; uint nd[4]; u64 rv[4];
      {
        const u64* s1b = h1rg + (size_t)(t & 7) * 1024;
#pragma unroll
        for (int e = 0; e < 4; e++) { ra[e] = s1b + tid + 256 * e; nd[e] = (uint)(t + 1); }
      }
      poll_recs<4>(ra, nd, rv);
      {
        f16* dst = h1c + (t & 1) * 2176;
#pragma unroll
        for (int e = 0; e < 4; e++) {
          int idx = tid + 256 * e;
          int bq = idx >> 8, r = idx & 255;
          int sqc = r >> 5, unc = r & 31;      // rec = sq*32+un
          uint pay = (uint)rv[e];
          dst[sqc * 136 + bq * 32 + unc]       = __builtin_bit_cast(f16, (ushort)pay);
          dst[(sqc + 8) * 136 + bq * 32 + unc] = __builtin_bit_cast(f16, (ushort)(pay >> 16));
        }
      }
      LBAR();
      if (tid == 0) STRLX(mytag, (uint)(t + 1));    // consumption signal (bp)
      f16x8 af0[4], af1[2];
#pragma unroll
      for (int kf = 0; kf < 4; kf++)
        af0[kf] = *(const f16x8*)&h1c[(t & 1) * 2176 + l16 * 136 + kf * 32 + quad * 8];
#pragma unroll
      for (int kf = 0; kf < 2; kf++)
        af1[kf] = *(const f16x8*)&h2db[(t & 1) * 1152 + l16 * 72 + kf * 32 + quad * 8];
      f32x4 z[4];
#pragma unroll
      for (int gm = 0; gm < 4; gm++) {
        f32x4 zz = {0.f, 0.f, 0.f, 0.f};
#pragma unroll
        for (int kf = 0; kf < 4; kf++)
          zz = MFMA16(af0[kf], wv8[((gm * 4 + w) * 4 + kf) * 64 + lane], zz);
#pragma unroll
        for (int kf = 0; kf < 2; kf++)
          zz = MFMA16(af1[kf], wv8[4096 + ((gm * 4 + w) * 2 + kf) * 64 + lane], zz);
        z[gm] = zz;
      }
#pragma unroll
      for (int r = 0; r < 4; r++) {
        float gi = sigm(z[0][r] + b2[0]);
        float ff = sigm(z[1][r] + b2[1]);
        float gg = reluf(z[2][r] + b2[2]);
        float oo = sigm(z[3][r] + b2[3]);
        c2[r] = ff * c2[r] + gi * gg;
        h2db[((t + 1) & 1) * 1152 + (quad * 4 + r) * 72 + 16 * w + l16] = (f16)(oo * reluf(c2[r]));
      }
    }
    __syncthreads();
    // dense tail -> feat cols 32..63 (agent-scope; head reads cross-XCD)
    float* zmA = (float*)smem;                // 16*132
    float* zmB = (float*)(smem + 8448);       // 16*68
    const f16* hf = h2db;                     // parity 0
#pragma unroll 1
    for (int e = 0; e < 8; e++) {
      const int idx = tid + 256 * e, sq = idx >> 7, j = idx & 127;
      float a = A.pd0b[j];
      for (int k = 0; k < 64; k++) a += (float)hf[sq * 72 + k] * A.pd0W[k * 128 + j];
      zmA[sq * 132 + j] = reluf(a);
    }
    __syncthreads();
#pragma unroll 1
    for (int e = 0; e < 4; e++) {
      const int idx = tid + 256 * e, sq = idx >> 6, j = idx & 63;
      float a = A.pd1b[j];
      for (int k = 0; k < 128; k++) a += zmA[sq * 132 + k] * A.pd1W[k * 64 + j];
      zmB[sq * 68 + j] = reluf(a);
    }
    __syncthreads();
#pragma unroll 1
    for (int e = 0; e < 2; e++) {
      const int idx = tid + 256 * e, sq = idx >> 5, j = idx & 31;
      float a = A.pd2b[j];
      for (int k = 0; k < 64; k++) a += zmB[sq * 68 + k] * A.pd2W[k * 32 + j];
      stf(A.feat + (g * 16 + sq) * 64 + 32 + j, a);
    }
    __syncthreads();                          // drain feat stores (vmcnt)
    if (tid == 0) STRLX(A.ffl + 8 + g, 1u);   // feat tile published
  } else if (role < 11) {
    // ================= title L0: units 64*bb.., 64KB LDS ====================
    const int bb = role - 9;
    f16* wlds = (f16*)smem;                  // [gm4][wv4][kf4][64]
    f16* hb   = (f16*)(smem + 65536);        // [2][16*136]
    {
      const uint4* U0tq = (const uint4*)A.U0tf;
      uint4* wq = (uint4*)wlds;
      for (int idx = tid; idx < 4096; idx += 256) {
        int gm = idx >> 10, r = idx & 1023, wv = r >> 8, kf = (r >> 6) & 3, ln = r & 63;
        wq[idx] = U0tq[((gm * 8 + 4 * bb + wv) * 4 + kf) * 64 + ln];
      }
    }
    for (int idx = tid; idx < 2176; idx += 256) hb[idx] = (f16)0.f;
    float c0[4] = {0.f, 0.f, 0.f, 0.f};
    u64* ringg = A.h0tr + (size_t)g * 8192;
    const u64* xtq = (const u64*)A.xt2;
    const f16x8* wv8 = (const f16x8*)wlds;
    const int myu = 64 * bb + 16 * w + l16;
    const int pbb = bb ^ 1;
    uint* bpp = A.cnt + (11 * 8 + g) * 16;
    uint* tflg = A.tfl + g * 16;
    __syncthreads();

    for (int t = 0; t < 64; t++) {
      {
        uint* pp = bpp; uint need = 0; bool act = false;
        if (lane == 0) { act = (t > 0) && ((t & 3) == 0); need = t > 4 ? (uint)(t - 4) : 0u; }
        else if (lane == 1) { act = ((t & 3) == 0); need = 1u; pp = tflg + (t >> 2); }
        poll_all(pp, need, act);
      }
      u64 xs[4];
      {
        size_t xb = ((size_t)(g * 64 + t) * 4) * 512 + (size_t)myu * 4 + quad;
#pragma unroll
        for (int gm = 0; gm < 4; gm++) xs[gm] = ldr64(xtq + xb + (size_t)gm * 512);
      }
      {
        const u64* ra[2]; uint nd[2]; u64 rv[2];
        const u64* rb = ringg + (size_t)((t + 7) & 7) * 1024 + pbb * 512 + 2 * tid;
        ra[0] = rb; ra[1] = rb + 1;
        nd[0] = nd[1] = (t > 0) ? (uint)t : 0u;
        poll_recs<2>(ra, nd, rv);
        if (t > 0) {
          f16* dst = hb + (t & 1) * 2176;
          const int ul = tid >> 2;
#pragma unroll
          for (int j = 0; j < 2; j++) {
            uint pay = (uint)rv[j];
            int r0 = ((tid & 3) * 2 + j) * 2;
            dst[r0 * 136 + pbb * 64 + ul]       = __builtin_bit_cast(f16, (ushort)pay);
            dst[(r0 + 1) * 136 + pbb * 64 + ul] = __builtin_bit_cast(f16, (ushort)(pay >> 16));
          }
        }
      }
      LBAR();
      f16x8 af[4];
#pragma unroll
      for (int kf = 0; kf < 4; kf++)
        af[kf] = *(const f16x8*)&hb[(t & 1) * 2176 + l16 * 136 + kf * 32 + quad * 8];
      f32x4 z[4];
#pragma unroll
      for (int gm = 0; gm < 4; gm++) {
        f32x4 zz = {0.f, 0.f, 0.f, 0.f};
#pragma unroll
        for (int kf = 0; kf < 4; kf++)
          zz = MFMA16(af[kf], wv8[((gm * 4 + w) * 4 + kf) * 64 + lane], zz);
        z[gm] = zz;
      }
      ushort hs[4];
      f16* wbuf = hb + ((t + 1) & 1) * 2176;
#pragma unroll
      for (int r = 0; r < 4; r++) {
        float gi = sigm(z[0][r] + h2f((ushort)(xs[0] >> (16 * r))));
        float ff = sigm(z[1][r] + h2f((ushort)(xs[1] >> (16 * r))));
        float gg = reluf(z[2][r] + h2f((ushort)(xs[2] >> (16 * r))));
        float oo = sigm(z[3][r] + h2f((ushort)(xs[3] >> (16 * r))));
        c0[r] = ff * c0[r] + gi * gg;
        hs[r] = f2h(oo * reluf(c0[r]));
        wbuf[(quad * 4 + r) * 136 + myu] = __builtin_bit_cast(f16, hs[r]);
      }
      {
        u64 tg = ((u64)(uint)(t + 1)) << 32;
        u64* wb = ringg + (size_t)(t & 7) * 1024 + bb * 512 + (16 * w + l16) * 8 + quad * 2;
        str64(wb,     tg | (u64)((uint)hs[0] | ((uint)hs[1] << 16)));
        str64(wb + 1, tg | (u64)((uint)hs[2] | ((uint)hs[3] << 16)));
      }
    }
  } else {
    // ================= title L1 + dense tail ================================
    f16* wlds = (f16*)smem;                  // W1t @0, U1t @4096 (f16x8 units)
    f16* h0tc = (f16*)(smem + 98304);        // [2][16*136]
    f16* h1db = (f16*)(smem + 107008);       // [2][16*72]
    {
      const uint4* W1tq = (const uint4*)A.W1tf;
      const uint4* U1tq = (const uint4*)A.U1tf;
      uint4* wq = (uint4*)wlds;
      for (int idx = tid; idx < 4096; idx += 256) wq[idx] = W1tq[idx];
      for (int idx = tid; idx < 2048; idx += 256) wq[4096 + idx] = U1tq[idx];
    }
    for (int idx = tid; idx < 1152; idx += 256) h1db[idx] = (f16)0.f;
    float c1[4] = {0.f, 0.f, 0.f, 0.f};
    float bt[4];
#pragma unroll
    for (int gm = 0; gm < 4; gm++) bt[gm] = A.tl1_b[gm * 64 + 16 * w + l16];
    u64* ringg = A.h0tr + (size_t)g * 8192;
    const f16x8* wv8 = (const f16x8*)wlds;
    __syncthreads();

    for (int t = 0; t < 64; t++) {
      const u64* ra[4]; uint nd[4]; u64 rv[4];
      {
        const u64* base = ringg + (size_t)(t & 7) * 1024;
#pragma unroll
        for (int e = 0; e < 4; e++) { ra[e] = base + tid + 256 * e; nd[e] = (uint)(t + 1); }
      }
      poll_recs<4>(ra, nd, rv);
      {
        f16* dst = h0tc + (t & 1) * 2176;
#pragma unroll
        for (int e = 0; e < 4; e++) {
          int idx = tid + 256 * e;
          int q = idx >> 9, rr = idx & 511, uls = rr >> 3, rp = rr & 7;
          uint pay = (uint)rv[e];
          dst[(2 * rp) * 136 + q * 64 + uls]     = __builtin_bit_cast(f16, (ushort)pay);
          dst[(2 * rp + 1) * 136 + q * 64 + uls] = __builtin_bit_cast(f16, (ushort)(pay >> 16));
        }
      }
      LBAR();
      if (tid == 0) STRLX(mytag, (uint)(t + 1));    // consumption signal (bp)
      f16x8 af0[4], af1[2];
#pragma unroll
      for (int kf = 0; kf < 4; kf++)
        af0[kf] = *(const f16x8*)&h0tc[(t & 1) * 2176 + l16 * 136 + kf * 32 + quad * 8];
#pragma unroll
      for (int kf = 0; kf < 2; kf++)
        af1[kf] = *(const f16x8*)&h1db[(t & 1) * 1152 + l16 * 72 + kf * 32 + quad * 8];
      f32x4 z[4];
#pragma unroll
      for (int gm = 0; gm < 4; gm++) {
        f32x4 zz = {0.f, 0.f, 0.f, 0.f};
#pragma unroll
        for (int kf = 0; kf < 4; kf++)
          zz = MFMA16(af0[kf], wv8[((gm * 4 + w) * 4 + kf) * 64 + lane], zz);
#pragma unroll
        for (int kf = 0; kf < 2; kf++)
          zz = MFMA16(af1[kf], wv8[4096 + ((gm * 4 + w) * 2 + kf) * 64 + lane], zz);
        z[gm] = zz;
      }
#pragma unroll
      for (int r = 0; r < 4; r++) {
        float gi = sigm(z[0][r] + bt[0]);
        float ff = sigm(z[1][r] + bt[1]);
        float gg = reluf(z[2][r] + bt[2]);
        float oo = sigm(z[3][r] + bt[3]);
        c1[r] = ff * c1[r] + gi * gg;
        h1db[((t + 1) & 1) * 1152 + (quad * 4 + r) * 72 + 16 * w + l16] = (f16)(oo * reluf(c1[r]));
      }
    }
    __syncthreads();
    // dense tail -> feat cols 0..31 (agent-scope; head reads cross-XCD)
    float* zmA = (float*)smem;
    float* zmB = (float*)(smem + 8448);
    const f16* hf = h1db;                    // parity 0
#pragma unroll 1
    for (int e = 0; e < 8; e++) {
      const int idx = tid + 256 * e, sq = idx >> 7, j = idx & 127;
      float a = A.td0b[j];
      for (int k = 0; k < 64; k++) a += (float)hf[sq * 72 + k] * A.td0W[k * 128 + j];
      zmA[sq * 132 + j] = reluf(a);
    }
    __syncthreads();
#pragma unroll 1
    for (int e = 0; e < 4; e++) {
      const int idx = tid + 256 * e, sq = idx >> 6, j = idx & 63;
      float a = A.td1b[j];
      for (int k = 0; k < 128; k++) a += zmA[sq * 132 + k] * A.td1W[k * 64 + j];
      zmB[sq * 68 + j] = reluf(a);
    }
    __syncthreads();
#pragma unroll 1
    for (int e = 0; e < 2; e++) {
      const int idx = tid + 256 * e, sq = idx >> 5, j = idx & 31;
      float a = A.td2b[j];
      for (int k = 0; k < 64; k++) a += zmB[sq * 68 + k] * A.td2W[k * 32 + j];
      stf(A.feat + (g * 16 + sq) * 64 + j, a);
    }
    __syncthreads();                          // drain feat stores (vmcnt)
    if (tid == 0) STRLX(A.ffl + g, 1u);       // feat tile published
  }
}

extern "C" void kernel_launch(void* const* d_in, const int* in_sizes, int n_in,
                              void* d_out, int out_size, void* d_ws, size_t ws_size,
                              hipStream_t stream) {
  const int*   t_tok = (const int*)d_in[0];
  const int*   p_tok = (const int*)d_in[1];
  const float* emb_t = (const float*)d_in[2];
  const float* emb_p = (const float*)d_in[3];
  const float* tl0_W = (const float*)d_in[4];
  const float* tl0_U = (const float*)d_in[5];
  const float* tl0_b = (const float*)d_in[6];
  const float* tl1_W = (const float*)d_in[7];
  const float* tl1_U = (const float*)d_in[8];
  const float* tl1_b = (const float*)d_in[9];
  const float* td0_W = (const float*)d_in[10];
  const float* td0_b = (const float*)d_in[11];
  const float* td1_W = (const float*)d_in[12];
  const float* td1_b = (const float*)d_in[13];
  const float* td2_W = (const float*)d_in[14];
  const float* td2_b = (const float*)d_in[15];
  const float* pl0_W = (const float*)d_in[16];
  const float* pl0_U = (const float*)d_in[17];
  const float* pl0_b = (const float*)d_in[18];
  const float* pl1_W = (const float*)d_in[19];
  const float* pl1_U = (const float*)d_in[20];
  const float* pl1_b = (const float*)d_in[21];
  const float* pl2_W = (const float*)d_in[22];
  const float* pl2_U = (const float*)d_in[23];
  const float* pl2_b = (const float*)d_in[24];
  const float* pd0_W = (const float*)d_in[25];
  const float* pd0_b = (const float*)d_in[26];
  const float* pd1_W = (const float*)d_in[27];
  const float* pd1_b = (const float*)d_in[28];
  const float* pd2_W = (const float*)d_in[29];
  const float* pd2_b = (const float*)d_in[30];
  const float* L0_W  = (const float*)d_in[31];
  const float* L0_b  = (const float*)d_in[32];
  const float* L1_W  = (const float*)d_in[33];
  const float* L1_b  = (const float*)d_in[34];
  const float* L2_W  = (const float*)d_in[35];
  const float* L2_b  = (const float*)d_in[36];
  const float* L3_W  = (const float*)d_in[37];
  const float* L3_b  = (const float*)d_in[38];

  char* ws = (char*)d_ws;
  size_t off = 0;
  auto alloc = [&](size_t bytes) {
    void* ptr = ws + off;
    off += (bytes + 255) & ~(size_t)255;
    return ptr;
  };
  f16* xp2  = (f16*)alloc((size_t)8 * 512 * 4 * 4096 * 2);     // 128 MB
  f16* xt2  = (f16*)alloc((size_t)8 * 64 * 4 * 2048 * 2);      // 8 MB
  f16* Bp   = (f16*)alloc((size_t)256 * 1024 * 2);
  f16* Bt   = (f16*)alloc((size_t)128 * 512 * 2);
  f16* U0f  = (f16*)alloc((size_t)256 * 1024 * 2);
  f16* W1f  = (f16*)alloc((size_t)256 * 512 * 2);
  f16* U1f  = (f16*)alloc((size_t)128 * 512 * 2);
  f16* W2f  = (f16*)alloc((size_t)128 * 256 * 2);
  f16* U2f  = (f16*)alloc((size_t)64 * 256 * 2);
  f16* U0tf = (f16*)alloc((size_t)128 * 512 * 2);
  f16* W1tf = (f16*)alloc((size_t)128 * 256 * 2);
  f16* U1tf = (f16*)alloc((size_t)64 * 256 * 2);
  size_t ringoff = off;
  u64* h0r  = (u64*)alloc((size_t)8 * 16384 * 8);              // 1 MB
  u64* h1r  = (u64*)alloc((size_t)8 * 8192 * 8);               // 512 KB
  u64* h0tr = (u64*)alloc((size_t)8 * 8192 * 8);               // 512 KB
  uint* cnt = (uint*)alloc((size_t)96 * 16 * 4);
  uint* xfl = (uint*)alloc((size_t)8 * 128 * 4);
  uint* tfl = (uint*)alloc((size_t)8 * 16 * 4);
  uint* ffl = (uint*)alloc((size_t)16 * 4);
  size_t ringlen = off - ringoff;
  float* feat = (float*)alloc((size_t)128 * 64 * 4);

  // ---- prep: 10 packs + ring/flag zeroing in ONE launch (stream-ordered
  // before fused; stale tags/flags from a prior replay would false-validate).
  PrepA pa;
  const float* srcs[10] = {tl0_W, pl0_W, pl0_U, pl1_W, pl1_U, pl2_W, pl2_U,
                           tl0_U, tl1_W, tl1_U};
  f16* dsts[10] = {Bt, Bp, U0f, W1f, U1f, W2f, U2f, U0tf, W1tf, U1tf};
  int kfs[10]   = {4, 8, 8, 8, 4, 4, 2, 4, 4, 2};
  int ns[10]    = {512, 1024, 1024, 512, 512, 256, 256, 512, 256, 256};
  int bsum = 0;
  for (int r = 0; r < 10; r++) {
    pa.src[r] = srcs[r]; pa.dst[r] = dsts[r];
    pa.kfm[r] = kfs[r] - 1;
    pa.lg[r]  = (kfs[r] == 8) ? 3 : (kfs[r] == 4 ? 2 : 1);
    pa.nn[r]  = ns[r];
    pa.total[r] = kfs[r] * 32 * ns[r];
    pa.bo[r] = bsum;
    bsum += pa.total[r] / 256;
  }
  pa.packBlocks = bsum;
  pa.zb = (u64*)(ws + ringoff);
  pa.zn = (long)(ringlen / 8);
  int zblocks = (int)((pa.zn + 255) / 256);
  prep<<<pa.packBlocks + zblocks, 256, 0, stream>>>(pa);

  RP ra;
  ra.t_tok = t_tok; ra.p_tok = p_tok; ra.emb_t = emb_t; ra.emb_p = emb_p;
  ra.Bp = Bp; ra.Bt = Bt; ra.tl0_b = tl0_b; ra.pl0_b = pl0_b;
  ra.xp2 = xp2; ra.xt2 = xt2;
  ra.U0f = U0f; ra.W1f = W1f; ra.U1f = U1f; ra.W2f = W2f; ra.U2f = U2f;
  ra.U0tf = U0tf; ra.W1tf = W1tf; ra.U1tf = U1tf;
  ra.pl1_b = pl1_b; ra.pl2_b = pl2_b; ra.tl1_b = tl1_b;
  ra.pd0W = pd0_W; ra.pd0b = pd0_b; ra.pd1W = pd1_W; ra.pd1b = pd1_b;
  ra.pd2W = pd2_W; ra.pd2b = pd2_b;
  ra.td0W = td0_W; ra.td0b = td0_b; ra.td1W = td1_W; ra.td1b = td1_b;
  ra.td2W = td2_W; ra.td2b = td2_b;
  ra.L0W = L0_W; ra.L0b = L0_b; ra.L1W = L1_W; ra.L1b = L1_b;
  ra.L2W = L2_W; ra.L2b = L2_b; ra.L3W = L3_W; ra.L3b = L3_b;
  ra.h0r = h0r; ra.h1r = h1r; ra.h0tr = h0tr;
  ra.cnt = cnt; ra.xfl = xfl; ra.tfl = tfl; ra.ffl = ffl;
  ra.feat = feat;
  ra.out = (float*)d_out;
  fused<<<256, 256, 0, stream>>>(ra);
}

// Round 10
// 1386.257 us; speedup vs baseline: 1.4183x; 1.0007x over previous
//
#include <hip/hip_runtime.h>
#include <hip/hip_fp16.h>

typedef _Float16 f16;
typedef _Float16 f16x8 __attribute__((ext_vector_type(8)));
typedef float    f32x4 __attribute__((ext_vector_type(4)));
typedef unsigned short ushort;
typedef unsigned int uint;
typedef unsigned long long u64;

__device__ __forceinline__ float sigm(float x) { return 1.f / (1.f + __expf(-x)); }
__device__ __forceinline__ float reluf(float x) { return x > 0.f ? x : 0.f; }
__device__ __forceinline__ float h2f(ushort u) { return (float)__builtin_bit_cast(f16, u); }
__device__ __forceinline__ ushort f2h(float v) { return __builtin_bit_cast(ushort, (f16)v); }

#define LDRLX(p)    __hip_atomic_load((p), __ATOMIC_RELAXED, __HIP_MEMORY_SCOPE_AGENT)
#define STRLX(p, v) __hip_atomic_store((p), (v), __ATOMIC_RELAXED, __HIP_MEMORY_SCOPE_AGENT)
#define MFMA16(a, b, c) __builtin_amdgcn_mfma_f32_16x16x32_f16((a), (b), (c), 0, 0, 0)
// lgkm-only barrier: orders LDS without draining vmcnt (ring publishes stay in
// flight across step barriers; correctness = tag-in-data + backpressure).
#define LBAR() do { asm volatile("s_waitcnt lgkmcnt(0)" ::: "memory"); \
                    __builtin_amdgcn_s_barrier(); } while (0)

__device__ __forceinline__ float ldf(const float* p) {
  return __hip_atomic_load(p, __ATOMIC_RELAXED, __HIP_MEMORY_SCOPE_AGENT);
}
__device__ __forceinline__ void stf(float* p, float v) {
  __hip_atomic_store(p, v, __ATOMIC_RELAXED, __HIP_MEMORY_SCOPE_AGENT);
}

// Backpressure / flag poll (agent scope; amortized off critical path — keeps
// its sleep quantum).
__device__ __forceinline__ void poll_all(uint* p, uint need, bool act) {
  bool done = !act;
  while (true) {
    if (!done) done = (LDRLX(p) >= need);
    if (__all((int)done)) break;
    __builtin_amdgcn_s_sleep(2);
  }
}

__device__ __forceinline__ u64 ldr64(const u64* p) {
  return __hip_atomic_load(p, __ATOMIC_RELAXED, __HIP_MEMORY_SCOPE_AGENT);
}
__device__ __forceinline__ void str64(u64* p, u64 v) {
  __hip_atomic_store(p, v, __ATOMIC_RELAXED, __HIP_MEMORY_SCOPE_AGENT);
}

// Tag-in-data record poll: each u64 record = {tag:32 | payload(2xf16):32}.
// R10: SLEEPLESS — this is the critical discovery path; retry loads are
// dependency-serialized (rate <= 1/RTT) so spinning adds no L3 pressure,
// and removing the s_sleep quantum cuts discovery latency per step.
template <int NR>
__device__ __forceinline__ void poll_recs(const u64* const (&ra)[NR],
                                          const uint (&nd)[NR], u64 (&rv)[NR]) {
  bool ok[NR];
#pragma unroll
  for (int i = 0; i < NR; i++) ok[i] = (nd[i] == 0u);
  while (true) {
    bool all = true;
#pragma unroll
    for (int i = 0; i < NR; i++) if (!ok[i]) rv[i] = ldr64(ra[i]);
#pragma unroll
    for (int i = 0; i < NR; i++) if (!ok[i]) ok[i] = ((uint)(rv[i] >> 32) >= nd[i]);
#pragma unroll
    for (int i = 0; i < NR; i++) all &= ok[i];
    if (all) return;
  }
}

// ---------------- prep: 10 pack regions (validated pack_bsw formula) + ring
// zeroing, consolidated into ONE launch.
struct PrepA {
  const float* src[10];
  f16* dst[10];
  int kfm[10];   // KF-1 (mask)
  int lg[10];    // log2(KF)
  int nn[10];    // N
  int total[10];
  int bo[10];    // starting block of region
  int packBlocks;
  u64* zb;       // zero base
  long zn;       // zero count (u64s)
};

__global__ __launch_bounds__(256) void prep(PrepA P) {
  const int blk = blockIdx.x;
  if (blk < P.packBlocks) {
    int r = 0;
#pragma unroll
    for (int i = 1; i < 10; i++) if (blk >= P.bo[i]) r = i;
    int id = (blk - P.bo[r]) * 256 + threadIdx.x;
    if (id < P.total[r]) {
      int j  = id & 7;
      int L  = (id >> 3) & 63;
      int rr = id >> 9;
      int kf = rr & P.kfm[r];
      int c  = rr >> P.lg[r];
      int k  = kf * 32 + ((L >> 4) * 8) + j;
      int n  = c * 16 + (L & 15);
      P.dst[r][id] = (f16)P.src[r][k * P.nn[r] + n];
    }
  } else {
    long i = (long)(blk - P.packBlocks) * 256 + threadIdx.x;
    if (i < P.zn) P.zb[i] = 0;
  }
}

struct RP {
  const int *t_tok, *p_tok;
  const float *emb_t, *emb_p;
  const f16 *Bp, *Bt;
  const float *tl0_b, *pl0_b;
  f16 *xp2, *xt2;
  const f16 *U0f, *W1f, *U1f, *W2f, *U2f, *U0tf, *W1tf, *U1tf;
  const float *pl1_b, *pl2_b, *tl1_b;
  const float *pd0W, *pd0b, *pd1W, *pd1b, *pd2W, *pd2b;
  const float *td0W, *td0b, *td1W, *td1b, *td2W, *td2b;
  const float *L0W, *L0b, *L1W, *L1b, *L2W, *L2b, *L3W, *L3b;
  u64 *h0r, *h1r, *h0tr;
  uint *cnt, *xfl, *tfl, *ffl;
  float* feat;
  float* out;
};

// ---------------- worker xW GEMM tile (R6 gemm_xw body; X stores are
// AGENT-SCOPE u64 so consumers on other XCDs see them without kernel-boundary
// flushes; trailing __syncthreads drains vmcnt before the caller's flag store).
template <int Sx, int K, int KF, int N, int NC, int MODE>
__device__ __forceinline__ void gemm_tile(int g, int t0,
    const int* __restrict__ tok, const float* __restrict__ emb,
    const f16* __restrict__ Bsw, const float* __restrict__ bias,
    u64* __restrict__ X, char* smem) {
  int* tokLds = (int*)smem;                  // 256B
  f16x8* bLds = (f16x8*)(smem + 1024);       // 8KB max
  const int tid = threadIdx.x;
  if (tid < 64) {
    int wv = tid >> 4, rho = tid & 15;
    tokLds[tid] = tok[(g * 16 + rho) * Sx + t0 + wv];
  }
  __syncthreads();
  const int wave = tid >> 6, lane = tid & 63;
  const int quad = lane >> 4, l16 = lane & 15;
  f16x8 a[KF];
  {
    const float* arow = emb + (long)tokLds[wave * 16 + l16] * K + quad * 8;
#pragma unroll
    for (int kf = 0; kf < KF; kf++) {
      float4 v0 = *(const float4*)(arow + kf * 32);
      float4 v1 = *(const float4*)(arow + kf * 32 + 4);
      f16x8 tv;
      tv[0] = (f16)v0.x; tv[1] = (f16)v0.y; tv[2] = (f16)v0.z; tv[3] = (f16)v0.w;
      tv[4] = (f16)v1.x; tv[5] = (f16)v1.y; tv[6] = (f16)v1.z; tv[7] = (f16)v1.w;
      a[kf] = tv;
    }
  }
  const int t = t0 + wave;
  const f16x8* Bfrag = (const f16x8*)Bsw;
  for (int c = 0; c < NC; c++) {
    __syncthreads();                         // prev iter's bLds readers done
    for (int i = tid; i < KF * 64; i += 256) bLds[i] = Bfrag[c * KF * 64 + i];
    __syncthreads();
    f32x4 acc = {0.f, 0.f, 0.f, 0.f};
#pragma unroll
    for (int kf = 0; kf < KF; kf++)
      acc = MFMA16(a[kf], bLds[kf * 64 + lane], acc);
    const int col = c * 16 + l16;
    const float bc = bias[col];
    uint lo = (uint)f2h(acc[0] + bc) | ((uint)f2h(acc[1] + bc) << 16);
    uint hi = (uint)f2h(acc[2] + bc) | ((uint)f2h(acc[3] + bc) << 16);
    u64 pv = (u64)lo | ((u64)hi << 32);
    size_t b64;
    if (MODE == 0) {
      int gm = col >> 8, u = col & 255;
      b64 = (((size_t)(g * 512 + t) * 4 + gm) * 1024) + u * 4 + quad;
    } else {
      int gm = col >> 7, u = col & 127;
      b64 = (((size_t)(g * 64 + t) * 4 + gm) * 512) + u * 4 + quad;
    }
    str64(X + b64, pv);
  }
  __syncthreads();                           // drain all waves' X stores
}

// ---------------- head (device body; runs in worker 159 after feat flags)
__device__ void head_body(const RP& A, char* smem) {
  const int tid = threadIdx.x;
  const int lane = tid & 63;
  poll_all(A.ffl + (lane & 15), 1u, lane < 16);   // all 16 feat tiles published
  __syncthreads();
  float* xb = (float*)smem;                // 512 f
  float* y0 = (float*)(smem + 2048);       // 2048 f
  float* y1 = (float*)(smem + 10240);      // 1024 f
  float* y2 = (float*)(smem + 14336);      // 512 f
  for (int idx = tid; idx < 512; idx += 256) {
    int b = idx >> 6, d = idx & 63;
    float s = 0.f;
    for (int n = 0; n < 16; n++) s += ldf(A.feat + (b * 16 + n) * 64 + d);
    xb[idx] = s * (1.f / 16.f);
  }
  __syncthreads();
  for (int idx = tid; idx < 2048; idx += 256) {
    int b = idx >> 8, j = idx & 255;
    float a = A.L0b[j];
    for (int k = 0; k < 64; k++) a += xb[b * 64 + k] * A.L0W[k * 256 + j];
    y0[idx] = reluf(a);
  }
  __syncthreads();
  for (int idx = tid; idx < 1024; idx += 256) {
    int b = idx >> 7, j = idx & 127;
    float a = A.L1b[j];
    for (int k = 0; k < 256; k++) a += y0[b * 256 + k] * A.L1W[k * 128 + j];
    y1[idx] = reluf(a);
  }
  __syncthreads();
  for (int idx = tid; idx < 512; idx += 256) {
    int b = idx >> 6, j = idx & 63;
    float a = A.L2b[j];
    for (int k = 0; k < 128; k++) a += y1[b * 128 + k] * A.L2W[k * 64 + j];
    y2[idx] = reluf(a);
  }
  __syncthreads();
  {
    int b = tid >> 5, j = tid & 31;
    float a = A.L3b[j];
    for (int k = 0; k < 64; k++) a += y2[b * 64 + k] * A.L3W[k * 32 + j];
    A.out[b * 32 + j] = 1.f / (1.f + __expf(-a));
  }
}

__device__ void worker_body(const RP& A, int wid, char* smem) {
  const int tid = threadIdx.x;
  // 1152 tiles ordered (tchunk, g), title first -> early timesteps first.
  for (int tile = wid; tile < 1152; tile += 160) {
    if (tile < 128) {
      int tch = tile >> 3, g = tile & 7;
      gemm_tile<64, 128, 4, 512, 32, 1>(g, tch * 4, A.t_tok, A.emb_t, A.Bt,
                                        A.tl0_b, (u64*)A.xt2, smem);
      if (tid == 0) STRLX(A.tfl + g * 16 + tch, 1u);
    } else {
      int m0 = tile - 128, tch = m0 >> 3, g = m0 & 7;
      gemm_tile<512, 256, 8, 1024, 64, 0>(g, tch * 4, A.p_tok, A.emb_p, A.Bp,
                                          A.pl0_b, (u64*)A.xp2, smem);
      if (tid == 0) STRLX(A.xfl + g * 128 + tch, 1u);
    }
  }
  if (wid == 159) head_body(A, smem);        // head folded into last worker
}

// ---------------- fused persistent kernel: 256 blocks x 256 thr.
// blk 0-95: R12/R6 recurrence (verified) — role = blk>>3, g = blk&7:
//   roles 0-3 paraL0(bb), 4-7 paraL1(bn), 8 paraL2+tail, 9-10 titleL0(bb),
//   11 titleL1+tail. blk 96-255: 160 xW-GEMM workers (tile queue + flags);
//   worker 159 additionally runs the HEAD after polling 16 feat flags.
// All 256 blocks are co-resident (148KB LDS -> 1 block/CU, grid == CU count),
// so the recur<->worker dependency cannot deadlock; workers terminate
// independently, so partial residency also makes progress.
// Cross-XCD data (X, feat) uses agent-scope stores AND loads; every
// flag/tag publish follows a vmcnt-draining __syncthreads (flag-visible =>
// data-visible). Rings/cnt/flags zeroed every replay (by prep).
// R10: L1 step barrier count 3 -> 2 (trailing LBAR proven redundant: next
// iteration's LBAR#1 orders zL reads vs zL writes and h1b writes vs af1
// reads; h0c scatter vs MFMA is covered by LBAR#2). Ring polls sleepless.
__global__ __launch_bounds__(256, 1) void fused(RP A) {
  __shared__ __align__(16) char smem[147968];
  const int blk = blockIdx.x;
  if (blk >= 96) { worker_body(A, blk - 96, smem); return; }
  const int tid = threadIdx.x;
  const int w = tid >> 6, lane = tid & 63;
  const int quad = lane >> 4, l16 = lane & 15;
  const int role = blk >> 3, g = blk & 7;
  uint* mytag = A.cnt + (role * 8 + g) * 16;

  if (role < 4) {
    // ================= paragraph L0: units 64*bb.. , weights 128KB LDS =======
    const int bb = role;
    f16* wlds = (f16*)smem;                 // [gm4][wv4][kf8][64] f16x8
    f16* hb   = (f16*)(smem + 131072);      // [2][16*264]
    {
      const uint4* U0q = (const uint4*)A.U0f;
      uint4* wq = (uint4*)wlds;
      for (int idx = tid; idx < 8192; idx += 256) {
        int gm = idx >> 11, r = idx & 2047, wv = r >> 9, kf = (r >> 6) & 7, ln = r & 63;
        wq[idx] = U0q[((gm * 16 + 4 * bb + wv) * 8 + kf) * 64 + ln];
      }
    }
    for (int idx = tid; idx < 4224; idx += 256) hb[idx] = (f16)0.f;
    float c0[4] = {0.f, 0.f, 0.f, 0.f};
    u64* ringg = A.h0r + (size_t)g * 16384;
    int pp3[3]; { int q = 0; for (int p = 0; p < 4; p++) if (p != bb) pp3[q++] = p; }
    const u64* xq2 = (const u64*)A.xp2;
    const f16x8* wv8 = (const f16x8*)wlds;
    const int myu = 64 * bb + 16 * w + l16;
    const int ulq = 16 * ((tid >> 4) & 3) + (tid & 15);   // coalesced-rec decode
    const int qd  = tid >> 6;
    uint* bpp = A.cnt;
    if (lane < 4) bpp = A.cnt + ((4 + lane) * 8 + g) * 16;
    uint* xflg = A.xfl + g * 128;
    __syncthreads();

    for (int t = 0; t < 512; t++) {
      {
        uint* pp = bpp; uint need = 0; bool act = false;
        if (lane < 4) { act = (t > 0) && ((t & 3) == 0); need = t > 4 ? (uint)(t - 4) : 0u; }
        else if (lane == 4) { act = ((t & 3) == 0); need = 1u; pp = xflg + (t >> 2); }
        poll_all(pp, need, act);
      }
      u64 xs[4];
      {
        size_t xb = ((size_t)(g * 512 + t) * 4) * 1024 + (size_t)myu * 4 + quad;
#pragma unroll
        for (int gm = 0; gm < 4; gm++) xs[gm] = ldr64(xq2 + xb + (size_t)gm * 1024);
      }
      {
        const u64* slotb = ringg + (size_t)((t + 7) & 7) * 2048;
        const u64* ra[6]; uint nd[6]; u64 rv[6];
#pragma unroll
        for (int q = 0; q < 3; q++) {
          const u64* rb = slotb + pp3[q] * 512 + 2 * tid;
          ra[q * 2] = rb; ra[q * 2 + 1] = rb + 1;
          nd[q * 2] = nd[q * 2 + 1] = (t > 0) ? (uint)t : 0u;
        }
        poll_recs<6>(ra, nd, rv);
        if (t > 0) {
          f16* dst = hb + (t & 1) * 4224;
#pragma unroll
          for (int q = 0; q < 3; q++)
#pragma unroll
            for (int j = 0; j < 2; j++) {
              uint pay = (uint)rv[q * 2 + j];
              int r0 = qd * 4 + 2 * j;
              dst[r0 * 264 + pp3[q] * 64 + ulq]       = __builtin_bit_cast(f16, (ushort)pay);
              dst[(r0 + 1) * 264 + pp3[q] * 64 + ulq] = __builtin_bit_cast(f16, (ushort)(pay >> 16));
            }
        }
      }
      LBAR();
      f16x8 af[8];
#pragma unroll
      for (int kf = 0; kf < 8; kf++)
        af[kf] = *(const f16x8*)&hb[(t & 1) * 4224 + l16 * 264 + kf * 32 + quad * 8];
      f32x4 z[4];
#pragma unroll
      for (int gm = 0; gm < 4; gm++) {
        f32x4 zz = {0.f, 0.f, 0.f, 0.f};
#pragma unroll
        for (int kf = 0; kf < 8; kf++)
          zz = MFMA16(af[kf], wv8[((gm * 4 + w) * 8 + kf) * 64 + lane], zz);
        z[gm] = zz;
      }
      ushort hs[4];
      f16* wbuf = hb + ((t + 1) & 1) * 4224;
#pragma unroll
      for (int r = 0; r < 4; r++) {
        float gi = sigm(z[0][r] + h2f((ushort)(xs[0] >> (16 * r))));
        float ff = sigm(z[1][r] + h2f((ushort)(xs[1] >> (16 * r))));
        float gg = reluf(z[2][r] + h2f((ushort)(xs[2] >> (16 * r))));
        float oo = sigm(z[3][r] + h2f((ushort)(xs[3] >> (16 * r))));
        c0[r] = ff * c0[r] + gi * gg;
        hs[r] = f2h(oo * reluf(c0[r]));
        wbuf[(quad * 4 + r) * 264 + myu] = __builtin_bit_cast(f16, hs[r]);
      }
      {
        // coalesced publish: rec = bb*512 + quad*128 + w*32 + l16*2 (+j)
        u64 tg = ((u64)(uint)(t + 1)) << 32;
        u64* wb = ringg + (size_t)(t & 7) * 2048 + bb * 512 +
                  quad * 128 + w * 32 + l16 * 2;
        str64(wb,     tg | (u64)((uint)hs[0] | ((uint)hs[1] << 16)));
        str64(wb + 1, tg | (u64)((uint)hs[2] | ((uint)hs[3] << 16)));
      }
    }
  } else if (role < 8) {
    // ================= paragraph L1: units 32*bn.., 96KB LDS weights ========
    const int bn = role - 4;
    f16* wlds = (f16*)smem;                  // W1 @0 (4096 x f16x8), U1 @4096
    f16* h0c  = (f16*)(smem + 98304);        // 16*264
    f16* h1b  = (f16*)(smem + 106752);       // [2][16*136]
    float* zL = (float*)(smem + 115456);     // 16*132
    {
      const uint4* W1q = (const uint4*)A.W1f;
      const uint4* U1q = (const uint4*)A.U1f;
      uint4* wq = (uint4*)wlds;
      for (int idx = tid; idx < 4096; idx += 256) {
        int gm = idx >> 10, r = idx & 1023, j2 = r >> 9, kf = (r >> 6) & 7, ln = r & 63;
        wq[idx] = W1q[((gm * 8 + bn * 2 + j2) * 8 + kf) * 64 + ln];
      }
      for (int idx = tid; idx < 2048; idx += 256) {
        int gm = idx >> 9, r = idx & 511, j2 = r >> 8, kf = (r >> 6) & 3, ln = r & 63;
        wq[4096 + idx] = U1q[((gm * 8 + bn * 2 + j2) * 4 + kf) * 64 + ln];
      }
    }
    for (int idx = tid; idx < 2176; idx += 256) h1b[idx] = (f16)0.f;
    float c1[2] = {0.f, 0.f};
    float bth[4];
    { int un = tid & 31; for (int gm = 0; gm < 4; gm++) bth[gm] = A.pl1_b[gm * 128 + 32 * bn + un]; }
    u64* h0rg = A.h0r + (size_t)g * 16384;
    u64* h1rg = A.h1r + (size_t)g * 8192;
    int pp3[3]; { int q = 0; for (int p = 0; p < 4; p++) if (p != bn) pp3[q++] = p; }
    const f16x8* wv8 = (const f16x8*)wlds;
    uint* bpp = A.cnt + (8 * 8 + g) * 16;
    __syncthreads();

    for (int t = 0; t < 512; t++) {
      {
        bool act = (lane == 0) && ((t & 3) == 0);
        uint need = t > 4 ? (uint)(t - 4) : 0u;
        poll_all(bpp, need, act);
      }
      const u64* ra[11]; uint nd[11]; u64 rv[11];
      {
        const u64* s0b = h0rg + (size_t)(t & 7) * 2048;
#pragma unroll
        for (int e = 0; e < 8; e++) { ra[e] = s0b + tid + 256 * e; nd[e] = (uint)(t + 1); }
        const u64* s1b = h1rg + (size_t)((t + 7) & 7) * 1024;
#pragma unroll
        for (int q = 0; q < 3; q++) { ra[8 + q] = s1b + pp3[q] * 256 + tid; nd[8 + q] = (t > 0) ? (uint)t : 0u; }
      }
      poll_recs<11>(ra, nd, rv);
      {
        // h0 scatter: decode coalesced rec idx -> (bb, quad, w, l16, j)
#pragma unroll
        for (int e = 0; e < 8; e++) {
          int idx = tid + 256 * e;
          int bbq = idx >> 9, r = idx & 511;
          int jj = r & 1, l16c = (r >> 1) & 15, wc = (r >> 5) & 3, qdc = (r >> 7) & 3;
          int col = bbq * 64 + 16 * wc + l16c;
          int r0 = qdc * 4 + 2 * jj;
          uint pay = (uint)rv[e];
          h0c[r0 * 264 + col]       = __builtin_bit_cast(f16, (ushort)pay);
          h0c[(r0 + 1) * 264 + col] = __builtin_bit_cast(f16, (ushort)(pay >> 16));
        }
        if (t > 0) {
          f16* dst = h1b + (t & 1) * 2176;
          int sqc = tid >> 5, unc = tid & 31;   // rec = sq*32+un = tid
#pragma unroll
          for (int q = 0; q < 3; q++) {
            uint pay = (uint)rv[8 + q];
            dst[sqc * 136 + pp3[q] * 32 + unc]       = __builtin_bit_cast(f16, (ushort)pay);
            dst[(sqc + 8) * 136 + pp3[q] * 32 + unc] = __builtin_bit_cast(f16, (ushort)(pay >> 16));
          }
        }
      }
      LBAR();
      if (tid == 0) STRLX(mytag, (uint)(t + 1));    // consumption signal (bp)
      f16x8 af0[8], af1[4];
#pragma unroll
      for (int kf = 0; kf < 8; kf++)
        af0[kf] = *(const f16x8*)&h0c[l16 * 264 + kf * 32 + quad * 8];
#pragma unroll
      for (int kf = 0; kf < 4; kf++)
        af1[kf] = *(const f16x8*)&h1b[(t & 1) * 2176 + l16 * 136 + kf * 32 + quad * 8];
#pragma unroll
      for (int j2 = 0; j2 < 2; j2++) {
        f32x4 zz = {0.f, 0.f, 0.f, 0.f};
#pragma unroll
        for (int kf = 0; kf < 8; kf++)
          zz = MFMA16(af0[kf], wv8[((w * 2 + j2) * 8 + kf) * 64 + lane], zz);
#pragma unroll
        for (int kf = 0; kf < 4; kf++)
          zz = MFMA16(af1[kf], wv8[4096 + ((w * 2 + j2) * 4 + kf) * 64 + lane], zz);
#pragma unroll
        for (int r = 0; r < 4; r++)
          zL[(quad * 4 + r) * 132 + w * 32 + j2 * 16 + l16] = zz[r];
      }
      LBAR();
      {
        int sq = tid >> 5, un = tid & 31;
        f16* dst = h1b + ((t + 1) & 1) * 2176;
        ushort hh[2];
#pragma unroll
        for (int e = 0; e < 2; e++) {
          int s = sq + 8 * e;
          float gi = sigm(zL[s * 132 + un] + bth[0]);
          float ff = sigm(zL[s * 132 + 32 + un] + bth[1]);
          float gg = reluf(zL[s * 132 + 64 + un] + bth[2]);
          float oo = sigm(zL[s * 132 + 96 + un] + bth[3]);
          c1[e] = ff * c1[e] + gi * gg;
          float hv = oo * reluf(c1[e]);
          hh[e] = f2h(hv);
          dst[s * 136 + 32 * bn + un] = __builtin_bit_cast(f16, hh[e]);
        }
        // coalesced publish: rec = bn*256 + tid (tid = sq*32+un)
        u64 tg = ((u64)(uint)(t + 1)) << 32;
        str64(h1rg + (size_t)(t & 7) * 1024 + bn * 256 + tid,
              tg | (u64)((uint)hh[0] | ((uint)hh[1] << 16)));
      }
      // R10: trailing LBAR removed — next iteration's LBAR#1 provides the
      // required LDS ordering (zL reads vs writes, h1b writes vs af1 reads);
      // h0c scatter(t+1) vs MFMA(t) is ordered by LBAR#2 above.
    }
  } else if (role == 8) {
    // ================= paragraph L2 + dense tail ============================
    f16* wlds = (f16*)smem;                  // W2 @0 (4096 f16x8), U2 @4096
    f16* h1c  = (f16*)(smem + 98304);        // [2][16*136]
    f16* h2db = (f16*)(smem + 107008);       // [2][16*72]
    {
      const uint4* W2q = (const uint4*)A.W2f;
      const uint4* U2q = (const uint4*)A.U2f;
      uint4* wq = (uint4*)wlds;
      for (int idx = tid; idx < 4096; idx += 256) wq[idx] = W2q[idx];
      for (int idx = tid; idx < 2048; idx += 256) wq[4096 + idx] = U2q[idx];
    }
    for (int idx = tid; idx < 1152; idx += 256) h2db[idx] = (f16)0.f;
    float c2[4] = {0.f, 0.f, 0.f, 0.f};
    float b2[4];
#pragma unroll
    for (int gm = 0; gm < 4; gm++) b2[gm] = A.pl2_b[gm * 64 + 16 * w + l16];
    u64* h1rg = A.h1r + (size_t)g * 8192;
    const f16x8* wv8 = (const f16x8*)wlds;
    __syncthreads();

    for (int t = 0; t < 512; t++) {
      const u64* ra[4]; uint nd[4]; u64 rv[4];
      {
        const u64* s1b = h1rg + (size_t)(t & 7) * 1024;
#pragma unroll
        for (int e = 0; e < 4; e++) { ra[e] = s1b + tid + 256 * e; nd[e] = (uint)(t + 1); }
      }
      poll_recs<4>(ra, nd, rv);
      {
        f16* dst = h1c + (t & 1) * 2176;
#pragma unroll
        for (int e = 0; e < 4; e++) {
          int idx = tid + 256 * e;
          int bq = idx >> 8, r = idx & 255;
          int sqc = r >> 5, unc = r & 31;      // rec = sq*32+un
          uint pay = (uint)rv[e];
          dst[sqc * 136 + bq * 32 + unc]       = __builtin_bit_cast(f16, (ushort)pay);
          dst[(sqc + 8) * 136 + bq * 32 + unc] = __builtin_bit_cast(f16, (ushort)(pay >> 16));
        }
      }
      LBAR();
      if (tid == 0) STRLX(mytag, (uint)(t + 1));    // consumption signal (bp)
      f16x8 af0[4], af1[2];
#pragma unroll
      for (int kf = 0; kf < 4; kf++)
        af0[kf] = *(const f16x8*)&h1c[(t & 1) * 2176 + l16 * 136 + kf * 32 + quad * 8];
#pragma unroll
      for (int kf = 0; kf < 2; kf++)
        af1[kf] = *(const f16x8*)&h2db[(t & 1) * 1152 + l16 * 72 + kf * 32 + quad * 8];
      f32x4 z[4];
#pragma unroll
      for (int gm = 0; gm < 4; gm++) {
        f32x4 zz = {0.f, 0.f, 0.f, 0.f};
#pragma unroll
        for (int kf = 0; kf < 4; kf++)
          zz = MFMA16(af0[kf], wv8[((gm * 4 + w) * 4 + kf) * 64 + lane], zz);
#pragma unroll
        for (int kf = 0; kf < 2; kf++)
          zz = MFMA16(af1[kf], wv8[4096 + ((gm * 4 + w) * 2 + kf) * 64 + lane], zz);
        z[gm] = zz;
      }
#pragma unroll
      for (int r = 0; r < 4; r++) {
        float gi = sigm(z[0][r] + b2[0]);
        float ff = sigm(z[1][r] + b2[1]);
        float gg = reluf(z[2][r] + b2[2]);
        float oo = sigm(z[3][r] + b2[3]);
        c2[r] = ff * c2[r] + gi * gg;
        h2db[((t + 1) & 1) * 1152 + (quad * 4 + r) * 72 + 16 * w + l16] = (f16)(oo * reluf(c2[r]));
      }
    }
    __syncthreads();
    // dense tail -> feat cols 32..63 (agent-scope; head reads cross-XCD)
    float* zmA = (float*)smem;                // 16*132
    float* zmB = (float*)(smem + 8448);       // 16*68
    const f16* hf = h2db;                     // parity 0
#pragma unroll 1
    for (int e = 0; e < 8; e++) {
      const int idx = tid + 256 * e, sq = idx >> 7, j = idx & 127;
      float a = A.pd0b[j];
      for (int k = 0; k < 64; k++) a += (float)hf[sq * 72 + k] * A.pd0W[k * 128 + j];
      zmA[sq * 132 + j] = reluf(a);
    }
    __syncthreads();
#pragma unroll 1
    for (int e = 0; e < 4; e++) {
      const int idx = tid + 256 * e, sq = idx >> 6, j = idx & 63;
      float a = A.pd1b[j];
      for (int k = 0; k < 128; k++) a += zmA[sq * 132 + k] * A.pd1W[k * 64 + j];
      zmB[sq * 68 + j] = reluf(a);
    }
    __syncthreads();
#pragma unroll 1
    for (int e = 0; e < 2; e++) {
      const int idx = tid + 256 * e, sq = idx >> 5, j = idx & 31;
      float a = A.pd2b[j];
      for (int k = 0; k < 64; k++) a += zmB[sq * 68 + k] * A.pd2W[k * 32 + j];
      stf(A.feat + (g * 16 + sq) * 64 + 32 + j, a);
    }
    __syncthreads();                          // drain feat stores (vmcnt)
    if (tid == 0) STRLX(A.ffl + 8 + g, 1u);   // feat tile published
  } else if (role < 11) {
    // ================= title L0: units 64*bb.., 64KB LDS ====================
    const int bb = role - 9;
    f16* wlds = (f16*)smem;                  // [gm4][wv4][kf4][64]
    f16* hb   = (f16*)(smem + 65536);        // [2][16*136]
    {
      const uint4* U0tq = (const uint4*)A.U0tf;
      uint4* wq = (uint4*)wlds;
      for (int idx = tid; idx < 4096; idx += 256) {
        int gm = idx >> 10, r = idx & 1023, wv = r >> 8, kf = (r >> 6) & 3, ln = r & 63;
        wq[idx] = U0tq[((gm * 8 + 4 * bb + wv) * 4 + kf) * 64 + ln];
      }
    }
    for (int idx = tid; idx < 2176; idx += 256) hb[idx] = (f16)0.f;
    float c0[4] = {0.f, 0.f, 0.f, 0.f};
    u64* ringg = A.h0tr + (size_t)g * 8192;
    const u64* xtq = (const u64*)A.xt2;
    const f16x8* wv8 = (const f16x8*)wlds;
    const int myu = 64 * bb + 16 * w + l16;
    const int pbb = bb ^ 1;
    uint* bpp = A.cnt + (11 * 8 + g) * 16;
    uint* tflg = A.tfl + g * 16;
    __syncthreads();

    for (int t = 0; t < 64; t++) {
      {
        uint* pp = bpp; uint need = 0; bool act = false;
        if (lane == 0) { act = (t > 0) && ((t & 3) == 0); need = t > 4 ? (uint)(t - 4) : 0u; }
        else if (lane == 1) { act = ((t & 3) == 0); need = 1u; pp = tflg + (t >> 2); }
        poll_all(pp, need, act);
      }
      u64 xs[4];
      {
        size_t xb = ((size_t)(g * 64 + t) * 4) * 512 + (size_t)myu * 4 + quad;
#pragma unroll
        for (int gm = 0; gm < 4; gm++) xs[gm] = ldr64(xtq + xb + (size_t)gm * 512);
      }
      {
        const u64* ra[2]; uint nd[2]; u64 rv[2];
        const u64* rb = ringg + (size_t)((t + 7) & 7) * 1024 + pbb * 512 + 2 * tid;
        ra[0] = rb; ra[1] = rb + 1;
        nd[0] = nd[1] = (t > 0) ? (uint)t : 0u;
        poll_recs<2>(ra, nd, rv);
        if (t > 0) {
          f16* dst = hb + (t & 1) * 2176;
          const int ul = tid >> 2;
#pragma unroll
          for (int j = 0; j < 2; j++) {
            uint pay = (uint)rv[j];
            int r0 = ((tid & 3) * 2 + j) * 2;
            dst[r0 * 136 + pbb * 64 + ul]       = __builtin_bit_cast(f16, (ushort)pay);
            dst[(r0 + 1) * 136 + pbb * 64 + ul] = __builtin_bit_cast(f16, (ushort)(pay >> 16));
          }
        }
      }
      LBAR();
      f16x8 af[4];
#pragma unroll
      for (int kf = 0; kf < 4; kf++)
        af[kf] = *(const f16x8*)&hb[(t & 1) * 2176 + l16 * 136 + kf * 32 + quad * 8];
      f32x4 z[4];
#pragma unroll
      for (int gm = 0; gm < 4; gm++) {
        f32x4 zz = {0.f, 0.f, 0.f, 0.f};
#pragma unroll
        for (int kf = 0; kf < 4; kf++)
          zz = MFMA16(af[kf], wv8[((gm * 4 + w) * 4 + kf) * 64 + lane], zz);
        z[gm] = zz;
      }
      ushort hs[4];
      f16* wbuf = hb + ((t + 1) & 1) * 2176;
#pragma unroll
      for (int r = 0; r < 4; r++) {
        float gi = sigm(z[0][r] + h2f((ushort)(xs[0] >> (16 * r))));
        float ff = sigm(z[1][r] + h2f((ushort)(xs[1] >> (16 * r))));
        float gg = reluf(z[2][r] + h2f((ushort)(xs[2] >> (16 * r))));
        float oo = sigm(z[3][r] + h2f((ushort)(xs[3] >> (16 * r))));
        c0[r] = ff * c0[r] + gi * gg;
        hs[r] = f2h(oo * reluf(c0[r]));
        wbuf[(quad * 4 + r) * 136 + myu] = __builtin_bit_cast(f16, hs[r]);
      }
      {
        u64 tg = ((u64)(uint)(t + 1)) << 32;
        u64* wb = ringg + (size_t)(t & 7) * 1024 + bb * 512 + (16 * w + l16) * 8 + quad * 2;
        str64(wb,     tg | (u64)((uint)hs[0] | ((uint)hs[1] << 16)));
        str64(wb + 1, tg | (u64)((uint)hs[2] | ((uint)hs[3] << 16)));
      }
    }
  } else {
    // ================= title L1 + dense tail ================================
    f16* wlds = (f16*)smem;                  // W1t @0, U1t @4096 (f16x8 units)
    f16* h0tc = (f16*)(smem + 98304);        // [2][16*136]
    f16* h1db = (f16*)(smem + 107008);       // [2][16*72]
    {
      const uint4* W1tq = (const uint4*)A.W1tf;
      const uint4* U1tq = (const uint4*)A.U1tf;
      uint4* wq = (uint4*)wlds;
      for (int idx = tid; idx < 4096; idx += 256) wq[idx] = W1tq[idx];
      for (int idx = tid; idx < 2048; idx += 256) wq[4096 + idx] = U1tq[idx];
    }
    for (int idx = tid; idx < 1152; idx += 256) h1db[idx] = (f16)0.f;
    float c1[4] = {0.f, 0.f, 0.f, 0.f};
    float bt[4];
#pragma unroll
    for (int gm = 0; gm < 4; gm++) bt[gm] = A.tl1_b[gm * 64 + 16 * w + l16];
    u64* ringg = A.h0tr + (size_t)g * 8192;
    const f16x8* wv8 = (const f16x8*)wlds;
    __syncthreads();

    for (int t = 0; t < 64; t++) {
      const u64* ra[4]; uint nd[4]; u64 rv[4];
      {
        const u64* base = ringg + (size_t)(t & 7) * 1024;
#pragma unroll
        for (int e = 0; e < 4; e++) { ra[e] = base + tid + 256 * e; nd[e] = (uint)(t + 1); }
      }
      poll_recs<4>(ra, nd, rv);
      {
        f16* dst = h0tc + (t & 1) * 2176;
#pragma unroll
        for (int e = 0; e < 4; e++) {
          int idx = tid + 256 * e;
          int q = idx >> 9, rr = idx & 511, uls = rr >> 3, rp = rr & 7;
          uint pay = (uint)rv[e];
          dst[(2 * rp) * 136 + q * 64 + uls]     = __builtin_bit_cast(f16, (ushort)pay);
          dst[(2 * rp + 1) * 136 + q * 64 + uls] = __builtin_bit_cast(f16, (ushort)(pay >> 16));
        }
      }
      LBAR();
      if (tid == 0) STRLX(mytag, (uint)(t + 1));    // consumption signal (bp)
      f16x8 af0[4], af1[2];
#pragma unroll
      for (int kf = 0; kf < 4; kf++)
        af0[kf] = *(const f16x8*)&h0tc[(t & 1) * 2176 + l16 * 136 + kf * 32 + quad * 8];
#pragma unroll
      for (int kf = 0; kf < 2; kf++)
        af1[kf] = *(const f16x8*)&h1db[(t & 1) * 1152 + l16 * 72 + kf * 32 + quad * 8];
      f32x4 z[4];
#pragma unroll
      for (int gm = 0; gm < 4; gm++) {
        f32x4 zz = {0.f, 0.f, 0.f, 0.f};
#pragma unroll
        for (int kf = 0; kf < 4; kf++)
          zz = MFMA16(af0[kf], wv8[((gm * 4 + w) * 4 + kf) * 64 + lane], zz);
#pragma unroll
        for (int kf = 0; kf < 2; kf++)
          zz = MFMA16(af1[kf], wv8[4096 + ((gm * 4 + w) * 2 + kf) * 64 + lane], zz);
        z[gm] = zz;
      }
#pragma unroll
      for (int r = 0; r < 4; r++) {
        float gi = sigm(z[0][r] + bt[0]);
        float ff = sigm(z[1][r] + bt[1]);
        float gg = reluf(z[2][r] + bt[2]);
        float oo = sigm(z[3][r] + bt[3]);
        c1[r] = ff * c1[r] + gi * gg;
        h1db[((t + 1) & 1) * 1152 + (quad * 4 + r) * 72 + 16 * w + l16] = (f16)(oo * reluf(c1[r]));
      }
    }
    __syncthreads();
    // dense tail -> feat cols 0..31 (agent-scope; head reads cross-XCD)
    float* zmA = (float*)smem;
    float* zmB = (float*)(smem + 8448);
    const f16* hf = h1db;                    // parity 0
#pragma unroll 1
    for (int e = 0; e < 8; e++) {
      const int idx = tid + 256 * e, sq = idx >> 7, j = idx & 127;
      float a = A.td0b[j];
      for (int k = 0; k < 64; k++) a += (float)hf[sq * 72 + k] * A.td0W[k * 128 + j];
      zmA[sq * 132 + j] = reluf(a);
    }
    __syncthreads();
#pragma unroll 1
    for (int e = 0; e < 4; e++) {
      const int idx = tid + 256 * e, sq = idx >> 6, j = idx & 63;
      float a = A.td1b[j];
      for (int k = 0; k < 128; k++) a += zmA[sq * 132 + k] * A.td1W[k * 64 + j];
      zmB[sq * 68 + j] = reluf(a);
    }
    __syncthreads();
#pragma unroll 1
    for (int e = 0; e < 2; e++) {
      const int idx = tid + 256 * e, sq = idx >> 5, j = idx & 31;
      float a = A.td2b[j];
      for (int k = 0; k < 64; k++) a += zmB[sq * 68 + k] * A.td2W[k * 32 + j];
      stf(A.feat + (g * 16 + sq) * 64 + j, a);
    }
    __syncthreads();                          // drain feat stores (vmcnt)
    if (tid == 0) STRLX(A.ffl + g, 1u);       // feat tile published
  }
}

extern "C" void kernel_launch(void* const* d_in, const int* in_sizes, int n_in,
                              void* d_out, int out_size, void* d_ws, size_t ws_size,
                              hipStream_t stream) {
  const int*   t_tok = (const int*)d_in[0];
  const int*   p_tok = (const int*)d_in[1];
  const float* emb_t = (const float*)d_in[2];
  const float* emb_p = (const float*)d_in[3];
  const float* tl0_W = (const float*)d_in[4];
  const float* tl0_U = (const float*)d_in[5];
  const float* tl0_b = (const float*)d_in[6];
  const float* tl1_W = (const float*)d_in[7];
  const float* tl1_U = (const float*)d_in[8];
  const float* tl1_b = (const float*)d_in[9];
  const float* td0_W = (const float*)d_in[10];
  const float* td0_b = (const float*)d_in[11];
  const float* td1_W = (const float*)d_in[12];
  const float* td1_b = (const float*)d_in[13];
  const float* td2_W = (const float*)d_in[14];
  const float* td2_b = (const float*)d_in[15];
  const float* pl0_W = (const float*)d_in[16];
  const float* pl0_U = (const float*)d_in[17];
  const float* pl0_b = (const float*)d_in[18];
  const float* pl1_W = (const float*)d_in[19];
  const float* pl1_U = (const float*)d_in[20];
  const float* pl1_b = (const float*)d_in[21];
  const float* pl2_W = (const float*)d_in[22];
  const float* pl2_U = (const float*)d_in[23];
  const float* pl2_b = (const float*)d_in[24];
  const float* pd0_W = (const float*)d_in[25];
  const float* pd0_b = (const float*)d_in[26];
  const float* pd1_W = (const float*)d_in[27];
  const float* pd1_b = (const float*)d_in[28];
  const float* pd2_W = (const float*)d_in[29];
  const float* pd2_b = (const float*)d_in[30];
  const float* L0_W  = (const float*)d_in[31];
  const float* L0_b  = (const float*)d_in[32];
  const float* L1_W  = (const float*)d_in[33];
  const float* L1_b  = (const float*)d_in[34];
  const float* L2_W  = (const float*)d_in[35];
  const float* L2_b  = (const float*)d_in[36];
  const float* L3_W  = (const float*)d_in[37];
  const float* L3_b  = (const float*)d_in[38];

  char* ws = (char*)d_ws;
  size_t off = 0;
  auto alloc = [&](size_t bytes) {
    void* ptr = ws + off;
    off += (bytes + 255) & ~(size_t)255;
    return ptr;
  };
  f16* xp2  = (f16*)alloc((size_t)8 * 512 * 4 * 4096 * 2);     // 128 MB
  f16* xt2  = (f16*)alloc((size_t)8 * 64 * 4 * 2048 * 2);      // 8 MB
  f16* Bp   = (f16*)alloc((size_t)256 * 1024 * 2);
  f16* Bt   = (f16*)alloc((size_t)128 * 512 * 2);
  f16* U0f  = (f16*)alloc((size_t)256 * 1024 * 2);
  f16* W1f  = (f16*)alloc((size_t)256 * 512 * 2);
  f16* U1f  = (f16*)alloc((size_t)128 * 512 * 2);
  f16* W2f  = (f16*)alloc((size_t)128 * 256 * 2);
  f16* U2f  = (f16*)alloc((size_t)64 * 256 * 2);
  f16* U0tf = (f16*)alloc((size_t)128 * 512 * 2);
  f16* W1tf = (f16*)alloc((size_t)128 * 256 * 2);
  f16* U1tf = (f16*)alloc((size_t)64 * 256 * 2);
  size_t ringoff = off;
  u64* h0r  = (u64*)alloc((size_t)8 * 16384 * 8);              // 1 MB
  u64* h1r  = (u64*)alloc((size_t)8 * 8192 * 8);               // 512 KB
  u64* h0tr = (u64*)alloc((size_t)8 * 8192 * 8);               // 512 KB
  uint* cnt = (uint*)alloc((size_t)96 * 16 * 4);
  uint* xfl = (uint*)alloc((size_t)8 * 128 * 4);
  uint* tfl = (uint*)alloc((size_t)8 * 16 * 4);
  uint* ffl = (uint*)alloc((size_t)16 * 4);
  size_t ringlen = off - ringoff;
  float* feat = (float*)alloc((size_t)128 * 64 * 4);

  // ---- prep: 10 packs + ring/flag zeroing in ONE launch (stream-ordered
  // before fused; stale tags/flags from a prior replay would false-validate).
  PrepA pa;
  const float* srcs[10] = {tl0_W, pl0_W, pl0_U, pl1_W, pl1_U, pl2_W, pl2_U,
                           tl0_U, tl1_W, tl1_U};
  f16* dsts[10] = {Bt, Bp, U0f, W1f, U1f, W2f, U2f, U0tf, W1tf, U1tf};
  int kfs[10]   = {4, 8, 8, 8, 4, 4, 2, 4, 4, 2};
  int ns[10]    = {512, 1024, 1024, 512, 512, 256, 256, 512, 256, 256};
  int bsum = 0;
  for (int r = 0; r < 10; r++) {
    pa.src[r] = srcs[r]; pa.dst[r] = dsts[r];
    pa.kfm[r] = kfs[r] - 1;
    pa.lg[r]  = (kfs[r] == 8) ? 3 : (kfs[r] == 4 ? 2 : 1);
    pa.nn[r]  = ns[r];
    pa.total[r] = kfs[r] * 32 * ns[r];
    pa.bo[r] = bsum;
    bsum += pa.total[r] / 256;
  }
  pa.packBlocks = bsum;
  pa.zb = (u64*)(ws + ringoff);
  pa.zn = (long)(ringlen / 8);
  int zblocks = (int)((pa.zn + 255) / 256);
  prep<<<pa.packBlocks + zblocks, 256, 0, stream>>>(pa);

  RP ra;
  ra.t_tok = t_tok; ra.p_tok = p_tok; ra.emb_t = emb_t; ra.emb_p = emb_p;
  ra.Bp = Bp; ra.Bt = Bt; ra.tl0_b = tl0_b; ra.pl0_b = pl0_b;
  ra.xp2 = xp2; ra.xt2 = xt2;
  ra.U0f = U0f; ra.W1f = W1f; ra.U1f = U1f; ra.W2f = W2f; ra.U2f = U2f;
  ra.U0tf = U0tf; ra.W1tf = W1tf; ra.U1tf = U1tf;
  ra.pl1_b = pl1_b; ra.pl2_b = pl2_b; ra.tl1_b = tl1_b;
  ra.pd0W = pd0_W; ra.pd0b = pd0_b; ra.pd1W = pd1_W; ra.pd1b = pd1_b;
  ra.pd2W = pd2_W; ra.pd2b = pd2_b;
  ra.td0W = td0_W; ra.td0b = td0_b; ra.td1W = td1_W; ra.td1b = td1_b;
  ra.td2W = td2_W; ra.td2b = td2_b;
  ra.L0W = L0_W; ra.L0b = L0_b; ra.L1W = L1_W; ra.L1b = L1_b;
  ra.L2W = L2_W; ra.L2b = L2_b; ra.L3W = L3_W; ra.L3b = L3_b;
  ra.h0r = h0r; ra.h1r = h1r; ra.h0tr = h0tr;
  ra.cnt = cnt; ra.xfl = xfl; ra.tfl = tfl; ra.ffl = ffl;
  ra.feat = feat;
  ra.out = (float*)d_out;
  fused<<<256, 256, 0, stream>>>(ra);
}